// Round 16
// baseline (177.614 us; speedup 1.0000x reference)
//
#include <hip/hip_runtime.h>

#define NB 16
#define HH 512
#define WW 512
#define HWN (HH * WW)            // 262144 = 1<<18
#define KC 512                    // max regions kept per image
#define RCAP 4096                 // root list capacity per image
#define CCAP 4096                 // tile-root slot capacity per image
#define PN (NB * HWN)
#define TPB 256
#define IMAX 0x7FFFFFFF
#define TS 64                     // CCL tile side
#define TSQ (TS * TS)             // 4096, local sentinel
#define NFIN (NB * 64)            // k_final grid (1024 blocks)

typedef unsigned short ushortT;
typedef unsigned int uintT;
typedef unsigned long long ullT;

// ---------------- union-find helpers (LDS, pixel-in-tile) ----------------
__device__ __forceinline__ int findRootL(int* s, int i) {
    int p = s[i];
    while (p != i) { i = p; p = s[i]; }
    return i;
}

__device__ __forceinline__ void uniteL(int* s, int a, int b) {
    int ra = findRootL(s, a);
    int rb = findRootL(s, b);
    while (ra != rb) {
        int lo = min(ra, rb), hi = max(ra, rb);
        int old = atomicMin(&s[hi], lo);
        if (old == hi) return;
        ra = old; rb = lo;
    }
}

// ---------------- union-find (slot space, packed key<<12|slot) ----------
// Monotone atomicMin: parent entries only decrease; min-key root wins.
// Works on LDS or global pointers.
__device__ __forceinline__ int rootPk(const int* par, int s) {
    int q = par[s];
    while ((q & (CCAP - 1)) != s) { s = q & (CCAP - 1); q = par[s]; }
    return q;                      // packed (key<<12|slot) of root
}

__device__ __forceinline__ void uniteS(int* par, int a, int b) {
    int pa = rootPk(par, a);
    int pb = rootPk(par, b);
    while (pa != pb) {
        int lo = min(pa, pb), hi = max(pa, pb);
        int hs = hi & (CCAP - 1);
        int old = atomicMin(&par[hs], lo);
        if (old == hi) return;
        pa = rootPk(par, old & (CCAP - 1));
        pb = rootPk(par, lo & (CCAP - 1));
    }
}

// binary search exact key in ascending array of KC ints (padded IMAX)
__device__ __forceinline__ int bsearch_k(const int* a, int key) {
    int lo = 0, hi = KC;
    while (lo < hi) { int m = (lo + hi) >> 1; if (a[m] < key) lo = m + 1; else hi = m; }
    return (lo < KC && a[lo] == key) ? lo : -1;
}

// ---------------- kernels ----------------
// Per-(tile,mask) CCL, prep fused: reads floats, ballots both masks locally,
// exports own-side row masks + edge-column masks, builds slot forest + stats.
__global__ __launch_bounds__(TPB) void k_local(const float* __restrict__ in, const float* __restrict__ tg,
                        ushortT* __restrict__ slotP, ushortT* __restrict__ slotG,
                        int* __restrict__ parP, int* __restrict__ parG,
                        ullT* __restrict__ rmPArr, ullT* __restrict__ rmGArr,
                        ullT* __restrict__ cmLP, ullT* __restrict__ cmRP,
                        ullT* __restrict__ cmLG, ullT* __restrict__ cmRG,
                        int* __restrict__ candCntP, int* __restrict__ candCntG,
                        int* __restrict__ sAreaP, int* __restrict__ sRP, int* __restrict__ sCP, int* __restrict__ sOvP,
                        int* __restrict__ sAreaG, int* __restrict__ sRG, int* __restrict__ sCG, int* __restrict__ sOvG) {
    __shared__ int s[TSQ];
    __shared__ ullT rm[TS], rmO[TS];
    int side = blockIdx.x & 1;
    int tileIdx = blockIdx.x >> 1;
    int b = tileIdx >> 6;               // 64 tiles per image (8x8)
    int tile = tileIdx & 63;
    int r0 = (tile >> 3) << 6, c0 = (tile & 7) << 6;
    int tc = tile & 7;
    int base = (b << 18) + (r0 << 9) + c0;
    int wv = threadIdx.x >> 6, lane = threadIdx.x & 63;

    const float* own = side ? tg : in;
    const float* oth = side ? in : tg;
    const float ownThr = side ? 0.5f : 0.0f;   // gt: >0.5 ; pred: sigmoid>0.5 <=> x>0
    const float othThr = side ? 0.0f : 0.5f;
    ushortT* slotArr = side ? slotG : slotP;
    int* par  = side ? parG : parP;
    ullT* rmOut = side ? rmGArr : rmPArr;
    ullT* cmLo = side ? cmLG : cmLP;
    ullT* cmRo = side ? cmRG : cmRP;
    int* candCnt = side ? candCntG : candCntP;
    int* sArea = side ? sAreaG : sAreaP;
    int* sR = side ? sRG : sRP;
    int* sC = side ? sCG : sCP;
    int* sOv = side ? sOvG : sOvP;

    // phase 0: read floats, ballot both masks (fused prep)
    #pragma unroll
    for (int k = 0; k < 16; k++) {
        int lr = wv + (k << 2);
        int gg = base + (lr << 9) + lane;
        ullT mp = __ballot(own[gg] > ownThr);
        ullT mq = __ballot(oth[gg] > othThr);
        if (lane == 0) { rm[lr] = mp; rmO[lr] = mq; }
    }
    __syncthreads();

    // phase 0b: export own-side row masks + edge-column masks (wave 0)
    if (threadIdx.x < 64) {
        ullT v = rm[threadIdx.x];
        int rowIdx = (((tc << 4) + b) << 9) + r0;
        rmOut[rowIdx + threadIdx.x] = v;
        ullT mL = __ballot((v & 1ULL) != 0);
        ullT mR = __ballot((v >> 63) != 0);
        if (threadIdx.x == 0) { cmLo[tileIdx] = mL; cmRo[tileIdx] = mR; }
    }

    // phase 1: run-start initial labels (no atomics, no ballots)
    #pragma unroll
    for (int k = 0; k < 16; k++) {
        int lr = wv + (k << 2);
        ullT mp = rm[lr];
        bool p = (mp >> lane) & 1ULL;
        int t = (lr << 6) + lane;
        ullT below = (lane == 0) ? 0ULL : ((~mp) & ((1ULL << lane) - 1ULL));
        int st = below ? (64 - __clzll(below)) : 0;
        s[t] = p ? ((lr << 6) + st) : TSQ;
    }
    __syncthreads();

    // phase 2: inter-row unions, reduced rules
    for (int lr = wv; lr < TS; lr += 4) {
        if (lr == 0) continue;
        int t = (lr << 6) + lane;
        ullT m = rm[lr], a = rm[lr - 1];
        if ((m >> lane) & 1ULL) {
            bool N  = (a >> lane) & 1ULL;
            bool W  = lane > 0  && ((m >> (lane - 1)) & 1ULL);
            bool NW = lane > 0  && ((a >> (lane - 1)) & 1ULL);
            bool E  = lane < 63 && ((m >> (lane + 1)) & 1ULL);
            bool NE = lane < 63 && ((a >> (lane + 1)) & 1ULL);
            if (N) { if (!(W && NW)) uniteL(s, t, t - TS); }
            else {
                if (NW && !W) uniteL(s, t, t - TS - 1);
                if (NE && !E) uniteL(s, t, t - TS + 1);
            }
        }
    }
    __syncthreads();

    // phase 3a: full path compression (racy-but-monotone, safe)
    #pragma unroll
    for (int k = 0; k < 16; k++) {
        int t = ((wv + (k << 2)) << 6) + lane;
        if (s[t] < TSQ) s[t] = findRootL(s, t);
    }
    __syncthreads();

    // phase 3b: roots -> slots (encode negative), packed par init
    #pragma unroll
    for (int k = 0; k < 16; k++) {
        int t = ((wv + (k << 2)) << 6) + lane;
        if (s[t] == t) {
            int pos = atomicAdd(&candCnt[b], 1);
            if (pos >= CCAP) pos = CCAP - 1;
            int gl = ((r0 + (t >> 6)) << 9) + (c0 + (t & 63));
            par[b * CCAP + pos] = (gl << 12) | pos;
            s[t] = -(pos + 2);
        }
    }
    __syncthreads();

    // phase 3c: per-pixel slot write + per-run stats
    #pragma unroll
    for (int k = 0; k < 16; k++) {
        int lr = wv + (k << 2);
        int t = (lr << 6) + lane;
        int g = base + (lr << 9) + lane;
        int vp = s[t];
        int slot = 0;
        if (vp != TSQ) slot = (vp < 0) ? (-vp - 1) : (-s[vp] - 1);
        slotArr[g] = (ushortT)slot;
        // run stats (run-start lanes only)
        ullT mp = rm[lr], mq = rmO[lr];
        bool isF = (mp >> lane) & 1ULL;
        if (isF && (lane == 0 || !((mp >> (lane - 1)) & 1ULL))) {
            ullT x = ~(mp >> lane);
            int len = x ? (__ffsll((long long)x) - 1) : (64 - lane);
            int sl = slot - 1;
            ullT runbits = (len >= 64) ? ~0ULL : (((1ULL << len) - 1ULL) << lane);
            atomicAdd(&sArea[b * CCAP + sl], len);
            atomicAdd(&sR[b * CCAP + sl], (r0 + lr) * len);
            atomicAdd(&sC[b * CCAP + sl], len * (c0 + lane) + (len * (len - 1)) / 2);
            if (mq & runbits) atomicOr(&sOv[b * CCAP + sl], 1);
        }
    }
}

// One block per IMAGE (512 thr): bmerge prologue on LDS par forests, then
// filter+sort root keys, slot->cid redux, centroid match, per-slot tables.
__global__ __launch_bounds__(512) void k_post(
        const ullT* __restrict__ rmP, const ullT* __restrict__ rmG,
        const ullT* __restrict__ cmLP, const ullT* __restrict__ cmRP,
        const ullT* __restrict__ cmLG, const ullT* __restrict__ cmRG,
        const ushortT* __restrict__ slotP, const ushortT* __restrict__ slotG,
        const int* __restrict__ parP, const int* __restrict__ parG,
        const int* __restrict__ candCntP, const int* __restrict__ candCntG,
        const int* __restrict__ sAreaP, const int* __restrict__ sRP, const int* __restrict__ sCP, const int* __restrict__ sOvP,
        const int* __restrict__ sAreaG, const int* __restrict__ sRG, const int* __restrict__ sCG, const int* __restrict__ sOvG,
        int* __restrict__ ccntG_g, float* __restrict__ vPs, float* __restrict__ vGs) {
    __shared__ int parL[2][CCAP];                 // slot forests, both sides
    __shared__ int s[RCAP];                       // sort buffer, later cid store
    __shared__ int compL[2][KC];
    __shared__ int stA[2][KC], stR[2][KC], stC[2][KC], stOv[2][KC];
    __shared__ float gAf[KC], gRf[KC], gCf[KC], sEG[KC], sFPl[KC], sFGl[KC];
    __shared__ int lcnt, ccX[2];
    int b = blockIdx.x;
    int tid = threadIdx.x;
    int wv8 = tid >> 6, lane = tid & 63;

    // phase 0: load par forests into LDS
    for (int t = tid; t < CCAP; t += 512) {
        parL[0][t] = parP[b * CCAP + t];
        parL[1][t] = parG[b * CCAP + t];
    }
    __syncthreads();

    // phase 0b: boundary merges (168 mask-driven tasks, LDS union-find)
    for (int task = wv8; task < 168; task += 8) {
        int type = task / 56;
        int sub = task % 56;
        int q = sub >> 3, t8 = sub & 7;
        for (int side = 0; side < 2; side++) {
            const ullT* rm = side ? rmG : rmP;
            const ullT* cmL = side ? cmLG : cmLP;
            const ullT* cmR = side ? cmRG : cmRP;
            const ushortT* S = (side ? slotG : slotP) + (b << 18);
            int* par = parL[side];

            if (type == 0) {        // horizontal boundary row r=64(q+1), chunk t8
                int r = (q + 1) << 6, tc = t8;
                int ib = (((tc << 4) + b) << 9);
                ullT m = rm[ib + r];
                if (!m) continue;
                ullT a = rm[ib + r - 1];
                ullT mW = 0, aW = 0, mE = 0, aE = 0;
                if (tc > 0) { int iw = ((((tc - 1) << 4) + b) << 9); mW = rm[iw + r]; aW = rm[iw + r - 1]; }
                if (tc < 7) { int ie = ((((tc + 1) << 4) + b) << 9); mE = rm[ie + r]; aE = rm[ie + r - 1]; }
                if ((m >> lane) & 1ULL) {
                    bool N  = (a >> lane) & 1ULL;
                    bool W  = lane ? ((m >> (lane - 1)) & 1ULL) : ((mW >> 63) & 1ULL);
                    bool NW = lane ? ((a >> (lane - 1)) & 1ULL) : ((aW >> 63) & 1ULL);
                    bool E  = (lane < 63) ? ((m >> (lane + 1)) & 1ULL) : (mE & 1ULL);
                    bool NE = (lane < 63) ? ((a >> (lane + 1)) & 1ULL) : (aE & 1ULL);
                    int i = (r << 9) + (tc << 6) + lane;
                    if (N) {
                        if (!(W && NW)) uniteS(par, S[i] - 1, S[i - WW] - 1);
                    } else {
                        if (NW && !W) uniteS(par, S[i] - 1, S[i - WW - 1] - 1);
                        if (NE && !E) uniteS(par, S[i] - 1, S[i - WW + 1] - 1);
                    }
                }
            } else if (type == 1) { // vertical boundary c=64(q+1), tile-row t8
                int c = (q + 1) << 6, tr = t8;
                int ownT = (b << 6) + (tr << 3) + (q + 1);
                int wstT = ownT - 1;
                ullT co = cmL[ownT];
                if (!co) continue;
                ullT cw = cmR[wstT];
                ullT coA = 0, cwA = 0;
                if (tr > 0) { coA = cmL[ownT - 8]; cwA = cmR[wstT - 8]; }
                int r = lane;
                if ((co >> r) & 1ULL) {
                    bool W  = (cw >> r) & 1ULL;
                    bool pO = r ? ((co >> (r - 1)) & 1ULL) : ((coA >> 63) & 1ULL);
                    bool pW = r ? ((cw >> (r - 1)) & 1ULL) : ((cwA >> 63) & 1ULL);
                    int i = (((tr << 6) + r) << 9) + c;
                    if (r == 0) {   // conservative at tile-top (breaks skip cycle)
                        if (W) uniteS(par, S[i] - 1, S[i - 1] - 1);
                        else if (pW) uniteS(par, S[i] - 1, S[i - WW - 1] - 1);
                    } else {
                        if (W) { if (!(pO && pW)) uniteS(par, S[i] - 1, S[i - 1] - 1); }
                        else if (pW && !pO) uniteS(par, S[i] - 1, S[i - WW - 1] - 1);
                    }
                }
            } else {                // NE edges at c=64q+63, tile-row t8
                int c = (q << 6) + 63, tr = t8;
                int ownT = (b << 6) + (tr << 3) + q;
                int estT = ownT + 1;
                ullT co = cmR[ownT];
                if (!co) continue;
                ullT ce = cmL[estT];
                ullT coA = 0, ceA = 0;
                if (tr > 0) { coA = cmR[ownT - 8]; ceA = cmL[estT - 8]; }
                int r = lane;
                if ((co >> r) & 1ULL) {
                    bool E  = (ce >> r) & 1ULL;
                    bool NE = r ? ((ce >> (r - 1)) & 1ULL) : ((ceA >> 63) & 1ULL);
                    bool pO = r ? ((co >> (r - 1)) & 1ULL) : false;   // conservative at r=0
                    if (NE && !E && !pO) {
                        int i = (((tr << 6) + r) << 9) + c;
                        uniteS(par, S[i] - 1, S[i - WW + 1] - 1);
                    }
                }
            }
        }
    }
    __syncthreads();

    // A: filter root slots + sort their pixel keys, build compact tables
    for (int side = 0; side < 2; side++) {
        const int* par = parL[side];
        int n = min((side ? candCntG : candCntP)[b], CCAP);
        if (tid == 0) lcnt = 0;
        __syncthreads();
        for (int t = tid; t < n; t += 512) {
            int pk = par[t];
            if ((pk & (CCAP - 1)) == t) { int pos = atomicAdd(&lcnt, 1); if (pos < RCAP) s[pos] = pk >> 12; }
        }
        __syncthreads();
        int nn2 = min(lcnt, RCAP);
        int m = 1; while (m < nn2) m <<= 1;
        for (int t = nn2 + tid; t < m; t += 512) s[t] = IMAX;
        __syncthreads();
        for (int k = 2; k <= m; k <<= 1) {
            for (int j = k >> 1; j > 0; j >>= 1) {
                for (int t = tid; t < m; t += 512) {
                    int ixj = t ^ j;
                    if (ixj > t) {
                        int a = s[t], bb = s[ixj];
                        bool up = ((t & k) == 0);
                        if ((a > bb) == up) { s[t] = bb; s[ixj] = a; }
                    }
                }
                __syncthreads();
            }
        }
        int cc = min(nn2, KC);
        for (int t = tid; t < KC; t += 512)
            compL[side][t] = (t < cc) ? s[t] : IMAX;
        if (tid == 0) { ccX[side] = cc; if (side) ccntG_g[b] = cc; }
        __syncthreads();
    }

    // B: zero LDS cid stats
    for (int t = tid; t < KC; t += 512) {
        stA[0][t] = 0; stR[0][t] = 0; stC[0][t] = 0; stOv[0][t] = 0;
        stA[1][t] = 0; stR[1][t] = 0; stC[1][t] = 0; stOv[1][t] = 0;
    }
    __syncthreads();

    // C: per-slot chase (LDS forest) + bsearch + aggregate
    short* cidS = (short*)s;
    for (int side = 0; side < 2; side++) {
        const int* par = parL[side];
        const int* aA = side ? sAreaG : sAreaP;
        const int* aR = side ? sRG : sRP;
        const int* aC = side ? sCG : sCP;
        const int* aO = side ? sOvG : sOvP;
        int n = min((side ? candCntG : candCntP)[b], CCAP);
        for (int slot = tid; slot < n; slot += 512) {
            int pk = rootPk(par, slot);
            int cid = bsearch_k(compL[side], pk >> 12);
            cidS[side * CCAP + slot] = (short)cid;
            if (cid >= 0) {
                int sidx = b * CCAP + slot;
                atomicAdd(&stA[side][cid], aA[sidx]);
                atomicAdd(&stR[side][cid], aR[sidx]);
                atomicAdd(&stC[side][cid], aC[sidx]);
                if (aO[sidx]) atomicOr(&stOv[side][cid], 1);
            }
        }
    }
    __syncthreads();

    // D: nearest gt centroid per pred region, region errors
    int t = tid;                                   // 512 == KC
    int ccg = ccX[1], ccp = ccX[0];
    {
        float fa = (float)stA[1][t];
        float d = fmaxf(fa, 1.0f);
        gAf[t] = fa;
        gRf[t] = (float)stR[1][t] / d;
        gCf[t] = (float)stC[1][t] / d;
        sEG[t] = 0.0f;
    }
    __syncthreads();
    float e_eff = 0.0f;
    int nn = 0;
    if (t < ccp) {
        float pa = (float)stA[0][t];
        float dd = fmaxf(pa, 1.0f);
        float pcr = (float)stR[0][t] / dd;
        float pcc = (float)stC[0][t] / dd;
        float best = INFINITY;
        for (int gi = 0; gi < ccg; gi++) {
            float dr = pcr - gRf[gi], dc = pcc - gCf[gi];
            float d2 = dr * dr + dc * dc;
            if (d2 < best) { best = d2; nn = gi; }  // first-min ties like argmin
        }
        if (ccg > 0 && stOv[0][t]) {
            float ratio = 1.0f - gAf[nn] / dd;
            e_eff = fminf(fabsf(1.0f - __expf(ratio)), 1.0f);
        }
    }
    if (e_eff > 0.0f) atomicMax((int*)&sEG[nn], __float_as_int(e_eff));
    sFPl[t] = stOv[0][t] ? e_eff : -1.0f;
    __syncthreads();
    sFGl[t] = stOv[1][t] ? fmaxf(sEG[t], 0.0f) : -1.0f;
    __syncthreads();

    // E: scatter per-slot value tables
    int nP = min(candCntP[b], CCAP), nG = min(candCntG[b], CCAP);
    for (int s2 = tid; s2 < nP; s2 += 512) {
        int cid = cidS[s2];
        vPs[b * CCAP + s2] = (cid >= 0) ? sFPl[cid] : -3.0f;   // -3 = fg w/o compact id
    }
    for (int s2 = tid; s2 < nG; s2 += 512) {
        int cid = cidS[CCAP + s2];
        vGs[b * CCAP + s2] = (cid >= 0) ? sFGl[cid] : 0.0f;
    }
}

// per-pixel error rules + fused loss/metric reduction: pure table lookups.
// 2 pixels per thread; per-block PARTIAL STORES (no global atomics).
__global__ __launch_bounds__(TPB) void k_final(const float* __restrict__ in,
                        const ushortT* __restrict__ slotP, const ushortT* __restrict__ slotG,
                        const float* __restrict__ vPs, const float* __restrict__ vGs,
                        const int* __restrict__ ccntG,
                        double* __restrict__ partLm, double* __restrict__ partPe,
                        double* __restrict__ partCnt) {
    __shared__ float pLm[4], pPe[4];
    __shared__ int pCnt[4];
    const uintT* sp2 = (const uintT*)slotP;
    const uintT* sg2 = (const uintT*)slotG;
    const float2* in2 = (const float2*)in;
    int b = blockIdx.x >> 6;            // 64 blocks per image, 2048 pairs each
    int blk = blockIdx.x & 63;
    bool hasGt = ccntG[b] > 0;
    const float* vP = vPs + b * CCAP;
    const float* vG = vGs + b * CCAP;
    float aLm = 0.0f, aPe = 0.0f;
    int aCnt = 0;
    #pragma unroll
    for (int k = 0; k < 8; k++) {
        int pidx = (b << 17) + (blk << 11) + (k << 8) + threadIdx.x;
        uintT up = sp2[pidx], ug = sg2[pidx];
        if (!__any(up | ug)) continue;   // whole wave background
        float pe0 = 0.0f, pe1 = 0.0f;
        {
            int fp = up & 0xffff, fg = ug & 0xffff;
            if (fp) {
                if (!hasGt) pe0 = 1.0f;
                else {
                    float v = vP[fp - 1];
                    if (v > -2.5f) { if (v < 0.0f) pe0 = 1.0f; else if (!fg) pe0 = v; }
                }
            }
            if (fg) {
                float vg = vG[fg - 1];
                if (!fp) pe0 = fmaxf(pe0, fmaxf(vg, 0.0f));
                if (vg < 0.0f) pe0 = 1.0f;
            }
        }
        {
            int fp = up >> 16, fg = ug >> 16;
            if (fp) {
                if (!hasGt) pe1 = 1.0f;
                else {
                    float v = vP[fp - 1];
                    if (v > -2.5f) { if (v < 0.0f) pe1 = 1.0f; else if (!fg) pe1 = v; }
                }
            }
            if (fg) {
                float vg = vG[fg - 1];
                if (!fp) pe1 = fmaxf(pe1, fmaxf(vg, 0.0f));
                if (vg < 0.0f) pe1 = 1.0f;
            }
        }
        if (pe0 != 0.0f || pe1 != 0.0f) {
            float2 x2 = in2[pidx];
            if (pe0 != 0.0f) {
                float score = 1.0f / (1.0f + __expf(-x2.x));
                aLm += (1.0f / (1.0f + __expf(-(score + 1.0f) * pe0)) - 0.5f) * 2.0f;
                aPe += pe0; aCnt++;
            }
            if (pe1 != 0.0f) {
                float score = 1.0f / (1.0f + __expf(-x2.y));
                aLm += (1.0f / (1.0f + __expf(-(score + 1.0f) * pe1)) - 0.5f) * 2.0f;
                aPe += pe1; aCnt++;
            }
        }
    }
    for (int o = 32; o; o >>= 1) {
        aLm += __shfl_xor(aLm, o);
        aPe += __shfl_xor(aPe, o);
        aCnt += __shfl_xor(aCnt, o);
    }
    int wv = threadIdx.x >> 6, lane = threadIdx.x & 63;
    if (lane == 0) { pLm[wv] = aLm; pPe[wv] = aPe; pCnt[wv] = aCnt; }
    __syncthreads();
    if (threadIdx.x == 0) {
        double sl = 0, sp = 0; int sc = 0;
        for (int q = 0; q < 4; q++) { sl += pLm[q]; sp += pPe[q]; sc += pCnt[q]; }
        partLm[blockIdx.x] = sl;
        partPe[blockIdx.x] = sp;
        partCnt[blockIdx.x] = (double)sc;
    }
}

// single-block reduction of the per-block partials -> 3 outputs
__global__ __launch_bounds__(TPB) void k_out(const double* __restrict__ partLm,
                                             const double* __restrict__ partPe,
                                             const double* __restrict__ partCnt,
                                             float* __restrict__ out) {
    __shared__ double r0[TPB], r1[TPB], r2[TPB];
    double sl = 0, sp = 0, sc = 0;
    for (int i = threadIdx.x; i < NFIN; i += TPB) {
        sl += partLm[i]; sp += partPe[i]; sc += partCnt[i];
    }
    r0[threadIdx.x] = sl; r1[threadIdx.x] = sp; r2[threadIdx.x] = sc;
    __syncthreads();
    for (int s = TPB >> 1; s > 0; s >>= 1) {
        if (threadIdx.x < s) {
            r0[threadIdx.x] += r0[threadIdx.x + s];
            r1[threadIdx.x] += r1[threadIdx.x + s];
            r2[threadIdx.x] += r2[threadIdx.x + s];
        }
        __syncthreads();
    }
    if (threadIdx.x == 0) {
        out[0] = (float)(r0[0] / (double)PN);
        out[1] = (float)(1.0 - r1[0] / (double)PN);
        out[2] = (float)(1.0 - r1[0] / r2[0]);
    }
}

extern "C" void kernel_launch(void* const* d_in, const int* in_sizes, int n_in,
                              void* d_out, int out_size, void* d_ws, size_t ws_size,
                              hipStream_t stream) {
    const float* in = (const float*)d_in[0];
    const float* tg = (const float*)d_in[1];
    // d_in[2] = epoch, unused by forward

    char* w = (char*)d_ws;
    size_t off = 0;
    ullT* rmP = (ullT*)(w + off); off += (size_t)(PN / 64) * 8;
    ullT* rmG = (ullT*)(w + off); off += (size_t)(PN / 64) * 8;
    ushortT* slotP = (ushortT*)(w + off); off += (size_t)PN * 2;
    ushortT* slotG = (ushortT*)(w + off); off += (size_t)PN * 2;
    int* parP = (int*)(w + off); off += (size_t)NB * CCAP * 4;
    int* parG = (int*)(w + off); off += (size_t)NB * CCAP * 4;
    ullT* cmLP = (ullT*)(w + off); off += (size_t)NB * 64 * 8;
    ullT* cmRP = (ullT*)(w + off); off += (size_t)NB * 64 * 8;
    ullT* cmLG = (ullT*)(w + off); off += (size_t)NB * 64 * 8;
    ullT* cmRG = (ullT*)(w + off); off += (size_t)NB * 64 * 8;
    float* vPs = (float*)(w + off); off += (size_t)NB * CCAP * 4;
    float* vGs = (float*)(w + off); off += (size_t)NB * CCAP * 4;
    int* ccntG = (int*)(w + off); off += NB * 4;
    double* partLm = (double*)(w + off); off += (size_t)NFIN * 8;
    double* partPe = (double*)(w + off); off += (size_t)NFIN * 8;
    double* partCnt = (double*)(w + off); off += (size_t)NFIN * 8;
    size_t zoff = off;
    int* candCntP = (int*)(w + off); off += NB * 4;
    int* candCntG = (int*)(w + off); off += NB * 4;
    int* sAreaP = (int*)(w + off); off += (size_t)NB * CCAP * 4;
    int* sRP    = (int*)(w + off); off += (size_t)NB * CCAP * 4;
    int* sCP    = (int*)(w + off); off += (size_t)NB * CCAP * 4;
    int* sOvP   = (int*)(w + off); off += (size_t)NB * CCAP * 4;
    int* sAreaG = (int*)(w + off); off += (size_t)NB * CCAP * 4;
    int* sRG    = (int*)(w + off); off += (size_t)NB * CCAP * 4;
    int* sCG    = (int*)(w + off); off += (size_t)NB * CCAP * 4;
    int* sOvG   = (int*)(w + off); off += (size_t)NB * CCAP * 4;
    size_t zend = off;

    // zero counters + slot stats (fresh every call)
    hipMemsetAsync(w + zoff, 0, zend - zoff, stream);

    k_local<<<NB * 64 * 2, TPB, 0, stream>>>(in, tg, slotP, slotG, parP, parG,
                                             rmP, rmG, cmLP, cmRP, cmLG, cmRG,
                                             candCntP, candCntG,
                                             sAreaP, sRP, sCP, sOvP,
                                             sAreaG, sRG, sCG, sOvG);
    k_post<<<NB, 512, 0, stream>>>(rmP, rmG, cmLP, cmRP, cmLG, cmRG,
                                   slotP, slotG, parP, parG,
                                   candCntP, candCntG,
                                   sAreaP, sRP, sCP, sOvP,
                                   sAreaG, sRG, sCG, sOvG,
                                   ccntG, vPs, vGs);
    k_final<<<NFIN, TPB, 0, stream>>>(in, slotP, slotG, vPs, vGs, ccntG,
                                      partLm, partPe, partCnt);
    k_out<<<1, TPB, 0, stream>>>(partLm, partPe, partCnt, (float*)d_out);
}

// Round 17
// 161.163 us; speedup vs baseline: 1.1021x; 1.1021x over previous
//
#include <hip/hip_runtime.h>

#define NB 16
#define HH 512
#define WW 512
#define HWN (HH * WW)            // 262144 = 1<<18
#define KC 512                    // max regions kept per image
#define RCAP 4096                 // root list capacity per image
#define CCAP 4096                 // tile-root slot capacity per image
#define PN (NB * HWN)
#define TPB 256
#define IMAX 0x7FFFFFFF
#define TS 64                     // CCL tile side
#define TSQ (TS * TS)             // 4096, local sentinel
#define NFIN (NB * 64)            // k_final grid (1024 blocks)

typedef unsigned short ushortT;
typedef unsigned int uintT;
typedef unsigned long long ullT;

// ---------------- union-find helpers (LDS, pixel-in-tile) ----------------
__device__ __forceinline__ int findRootL(int* s, int i) {
    int p = s[i];
    while (p != i) { i = p; p = s[i]; }
    return i;
}

__device__ __forceinline__ void uniteL(int* s, int a, int b) {
    int ra = findRootL(s, a);
    int rb = findRootL(s, b);
    while (ra != rb) {
        int lo = min(ra, rb), hi = max(ra, rb);
        int old = atomicMin(&s[hi], lo);
        if (old == hi) return;
        ra = old; rb = lo;
    }
}

// ---------------- union-find (slot space, packed key<<12|slot) ----------
// Monotone atomicMin: parent entries only decrease; min-key root wins.
__device__ __forceinline__ int rootPk(const int* par, int s) {
    int q = par[s];
    while ((q & (CCAP - 1)) != s) { s = q & (CCAP - 1); q = par[s]; }
    return q;                      // packed (key<<12|slot) of root
}

__device__ __forceinline__ void uniteS(int* par, int a, int b) {
    int pa = rootPk(par, a);
    int pb = rootPk(par, b);
    while (pa != pb) {
        int lo = min(pa, pb), hi = max(pa, pb);
        int hs = hi & (CCAP - 1);
        int old = atomicMin(&par[hs], lo);
        if (old == hi) return;
        pa = rootPk(par, old & (CCAP - 1));
        pb = rootPk(par, lo & (CCAP - 1));
    }
}

// binary search exact key in ascending array of KC ints (padded IMAX)
__device__ __forceinline__ int bsearch_k(const int* a, int key) {
    int lo = 0, hi = KC;
    while (lo < hi) { int m = (lo + hi) >> 1; if (a[m] < key) lo = m + 1; else hi = m; }
    return (lo < KC && a[lo] == key) ? lo : -1;
}

// ---------------- kernels ----------------
// Streaming prepass (float4-vectorized): threshold both masks, assemble
// 64-bit row-chunk masks via 16-lane shfl-OR reduction.
// Layout: rm[((tc*NB + b) << 9) + r]  (tc = column chunk 0..7).
__global__ __launch_bounds__(TPB) void k_prep(const float* __restrict__ in, const float* __restrict__ tg,
                                              ullT* __restrict__ rmP, ullT* __restrict__ rmG) {
    int lane = threadIdx.x & 63;
    int wid = (blockIdx.x * blockDim.x + threadIdx.x) >> 6;   // 8192 waves
    const float4* in4 = (const float4*)in;
    const float4* tg4 = (const float4*)tg;
    #pragma unroll
    for (int it = 0; it < 2; it++) {
        int span = wid + (it << 13);          // 16384 spans of 256 px
        int vidx = (span << 6) + lane;        // float4 index
        float4 a = in4[vidx];
        float4 t4 = tg4[vidx];
        uintT bp = (a.x > 0.0f) | ((a.y > 0.0f) << 1) | ((a.z > 0.0f) << 2) | ((a.w > 0.0f) << 3);
        uintT bg = (t4.x > 0.5f) | ((t4.y > 0.5f) << 1) | ((t4.z > 0.5f) << 2) | ((t4.w > 0.5f) << 3);
        ullT vp = (ullT)bp << ((lane & 15) << 2);
        ullT vg = (ullT)bg << ((lane & 15) << 2);
        #pragma unroll
        for (int o = 1; o < 16; o <<= 1) {
            vp |= __shfl_xor(vp, o);
            vg |= __shfl_xor(vg, o);
        }
        if ((lane & 15) == 0) {
            int g = (span << 8) + ((lane >> 4) << 6);
            int b = g >> 18, r = (g >> 9) & 511, tc = (g >> 6) & 7;
            int idx = (((tc << 4) + b) << 9) + r;
            rmP[idx] = vp; rmG[idx] = vg;
        }
    }
}

// Per-(tile,mask) CCL from row masks (round-13 version).
__global__ __launch_bounds__(TPB) void k_local(const ullT* __restrict__ rmPArr, const ullT* __restrict__ rmGArr,
                        ushortT* __restrict__ slotP, ushortT* __restrict__ slotG,
                        int* __restrict__ parP, int* __restrict__ parG,
                        ullT* __restrict__ cmLP, ullT* __restrict__ cmRP,
                        ullT* __restrict__ cmLG, ullT* __restrict__ cmRG,
                        int* __restrict__ candCntP, int* __restrict__ candCntG,
                        int* __restrict__ sAreaP, int* __restrict__ sRP, int* __restrict__ sCP, int* __restrict__ sOvP,
                        int* __restrict__ sAreaG, int* __restrict__ sRG, int* __restrict__ sCG, int* __restrict__ sOvG) {
    __shared__ int s[TSQ];
    __shared__ ullT rm[TS], rmO[TS];
    int side = blockIdx.x & 1;
    int tileIdx = blockIdx.x >> 1;
    int b = tileIdx >> 6;               // 64 tiles per image (8x8)
    int tile = tileIdx & 63;
    int r0 = (tile >> 3) << 6, c0 = (tile & 7) << 6;
    int tc = tile & 7;
    int base = (b << 18) + (r0 << 9) + c0;
    int wv = threadIdx.x >> 6, lane = threadIdx.x & 63;

    const ullT* own = side ? rmGArr : rmPArr;
    const ullT* oth = side ? rmPArr : rmGArr;
    ushortT* slotArr = side ? slotG : slotP;
    int* par  = side ? parG : parP;
    ullT* cmLo = side ? cmLG : cmLP;
    ullT* cmRo = side ? cmRG : cmRP;
    int* candCnt = side ? candCntG : candCntP;
    int* sArea = side ? sAreaG : sAreaP;
    int* sR = side ? sRG : sRP;
    int* sC = side ? sCG : sCP;
    int* sOv = side ? sOvG : sOvP;

    // phase 0: load 64+64 row masks (512B each, contiguous)
    int rowIdx = (((tc << 4) + b) << 9) + r0;
    if (threadIdx.x < 64) rm[threadIdx.x] = own[rowIdx + threadIdx.x];
    else if (threadIdx.x < 128) rmO[threadIdx.x - 64] = oth[rowIdx + threadIdx.x - 64];
    __syncthreads();

    // phase 0b: export edge-column masks (wave 0: lane = row)
    if (threadIdx.x < 64) {
        ullT v = rm[threadIdx.x];
        ullT mL = __ballot((v & 1ULL) != 0);
        ullT mR = __ballot((v >> 63) != 0);
        if (threadIdx.x == 0) { cmLo[tileIdx] = mL; cmRo[tileIdx] = mR; }
    }

    // phase 1: run-start initial labels (no atomics, no ballots)
    #pragma unroll
    for (int k = 0; k < 16; k++) {
        int lr = wv + (k << 2);
        ullT mp = rm[lr];
        bool p = (mp >> lane) & 1ULL;
        int t = (lr << 6) + lane;
        ullT below = (lane == 0) ? 0ULL : ((~mp) & ((1ULL << lane) - 1ULL));
        int st = below ? (64 - __clzll(below)) : 0;
        s[t] = p ? ((lr << 6) + st) : TSQ;
    }
    __syncthreads();

    // phase 2: inter-row unions, reduced rules
    for (int lr = wv; lr < TS; lr += 4) {
        if (lr == 0) continue;
        int t = (lr << 6) + lane;
        ullT m = rm[lr], a = rm[lr - 1];
        if ((m >> lane) & 1ULL) {
            bool N  = (a >> lane) & 1ULL;
            bool W  = lane > 0  && ((m >> (lane - 1)) & 1ULL);
            bool NW = lane > 0  && ((a >> (lane - 1)) & 1ULL);
            bool E  = lane < 63 && ((m >> (lane + 1)) & 1ULL);
            bool NE = lane < 63 && ((a >> (lane + 1)) & 1ULL);
            if (N) { if (!(W && NW)) uniteL(s, t, t - TS); }
            else {
                if (NW && !W) uniteL(s, t, t - TS - 1);
                if (NE && !E) uniteL(s, t, t - TS + 1);
            }
        }
    }
    __syncthreads();

    // phase 3a: full path compression (racy-but-monotone, safe)
    #pragma unroll
    for (int k = 0; k < 16; k++) {
        int t = ((wv + (k << 2)) << 6) + lane;
        if (s[t] < TSQ) s[t] = findRootL(s, t);
    }
    __syncthreads();

    // phase 3b: roots -> slots (encode negative), packed par init
    #pragma unroll
    for (int k = 0; k < 16; k++) {
        int t = ((wv + (k << 2)) << 6) + lane;
        if (s[t] == t) {
            int pos = atomicAdd(&candCnt[b], 1);
            if (pos >= CCAP) pos = CCAP - 1;
            int gl = ((r0 + (t >> 6)) << 9) + (c0 + (t & 63));
            par[b * CCAP + pos] = (gl << 12) | pos;
            s[t] = -(pos + 2);
        }
    }
    __syncthreads();

    // phase 3c: per-pixel slot write + per-run stats
    #pragma unroll
    for (int k = 0; k < 16; k++) {
        int lr = wv + (k << 2);
        int t = (lr << 6) + lane;
        int g = base + (lr << 9) + lane;
        int vp = s[t];
        int slot = 0;
        if (vp != TSQ) slot = (vp < 0) ? (-vp - 1) : (-s[vp] - 1);
        slotArr[g] = (ushortT)slot;
        // run stats (run-start lanes only)
        ullT mp = rm[lr], mq = rmO[lr];
        bool isF = (mp >> lane) & 1ULL;
        if (isF && (lane == 0 || !((mp >> (lane - 1)) & 1ULL))) {
            ullT x = ~(mp >> lane);
            int len = x ? (__ffsll((long long)x) - 1) : (64 - lane);
            int sl = slot - 1;
            ullT runbits = (len >= 64) ? ~0ULL : (((1ULL << len) - 1ULL) << lane);
            atomicAdd(&sArea[b * CCAP + sl], len);
            atomicAdd(&sR[b * CCAP + sl], (r0 + lr) * len);
            atomicAdd(&sC[b * CCAP + sl], len * (c0 + lane) + (len * (len - 1)) / 2);
            if (mq & runbits) atomicOr(&sOv[b * CCAP + sl], 1);
        }
    }
}

// One block per IMAGE (512 thr): bmerge prologue on LDS par forests, then
// filter+sort root keys, slot->cid redux, centroid match, per-slot tables.
__global__ __launch_bounds__(512) void k_post(
        const ullT* __restrict__ rmP, const ullT* __restrict__ rmG,
        const ullT* __restrict__ cmLP, const ullT* __restrict__ cmRP,
        const ullT* __restrict__ cmLG, const ullT* __restrict__ cmRG,
        const ushortT* __restrict__ slotP, const ushortT* __restrict__ slotG,
        const int* __restrict__ parP, const int* __restrict__ parG,
        const int* __restrict__ candCntP, const int* __restrict__ candCntG,
        const int* __restrict__ sAreaP, const int* __restrict__ sRP, const int* __restrict__ sCP, const int* __restrict__ sOvP,
        const int* __restrict__ sAreaG, const int* __restrict__ sRG, const int* __restrict__ sCG, const int* __restrict__ sOvG,
        int* __restrict__ ccntG_g, float* __restrict__ vPs, float* __restrict__ vGs) {
    __shared__ int parL[2][CCAP];                 // slot forests, both sides
    __shared__ int s[RCAP];                       // sort buffer, later cid store
    __shared__ int compL[2][KC];
    __shared__ int stA[2][KC], stR[2][KC], stC[2][KC], stOv[2][KC];
    __shared__ float gAf[KC], gRf[KC], gCf[KC], sEG[KC], sFPl[KC], sFGl[KC];
    __shared__ int lcnt, ccX[2];
    int b = blockIdx.x;
    int tid = threadIdx.x;
    int wv8 = tid >> 6, lane = tid & 63;

    // phase 0: load par forests into LDS
    for (int t = tid; t < CCAP; t += 512) {
        parL[0][t] = parP[b * CCAP + t];
        parL[1][t] = parG[b * CCAP + t];
    }
    __syncthreads();

    // phase 0b: boundary merges (168 mask-driven tasks, LDS union-find)
    for (int task = wv8; task < 168; task += 8) {
        int type = task / 56;
        int sub = task % 56;
        int q = sub >> 3, t8 = sub & 7;
        for (int side = 0; side < 2; side++) {
            const ullT* rm = side ? rmG : rmP;
            const ullT* cmL = side ? cmLG : cmLP;
            const ullT* cmR = side ? cmRG : cmRP;
            const ushortT* S = (side ? slotG : slotP) + (b << 18);
            int* par = parL[side];

            if (type == 0) {        // horizontal boundary row r=64(q+1), chunk t8
                int r = (q + 1) << 6, tc = t8;
                int ib = (((tc << 4) + b) << 9);
                ullT m = rm[ib + r];
                if (!m) continue;
                ullT a = rm[ib + r - 1];
                ullT mW = 0, aW = 0, mE = 0, aE = 0;
                if (tc > 0) { int iw = ((((tc - 1) << 4) + b) << 9); mW = rm[iw + r]; aW = rm[iw + r - 1]; }
                if (tc < 7) { int ie = ((((tc + 1) << 4) + b) << 9); mE = rm[ie + r]; aE = rm[ie + r - 1]; }
                if ((m >> lane) & 1ULL) {
                    bool N  = (a >> lane) & 1ULL;
                    bool W  = lane ? ((m >> (lane - 1)) & 1ULL) : ((mW >> 63) & 1ULL);
                    bool NW = lane ? ((a >> (lane - 1)) & 1ULL) : ((aW >> 63) & 1ULL);
                    bool E  = (lane < 63) ? ((m >> (lane + 1)) & 1ULL) : (mE & 1ULL);
                    bool NE = (lane < 63) ? ((a >> (lane + 1)) & 1ULL) : (aE & 1ULL);
                    int i = (r << 9) + (tc << 6) + lane;
                    if (N) {
                        if (!(W && NW)) uniteS(par, S[i] - 1, S[i - WW] - 1);
                    } else {
                        if (NW && !W) uniteS(par, S[i] - 1, S[i - WW - 1] - 1);
                        if (NE && !E) uniteS(par, S[i] - 1, S[i - WW + 1] - 1);
                    }
                }
            } else if (type == 1) { // vertical boundary c=64(q+1), tile-row t8
                int c = (q + 1) << 6, tr = t8;
                int ownT = (b << 6) + (tr << 3) + (q + 1);
                int wstT = ownT - 1;
                ullT co = cmL[ownT];
                if (!co) continue;
                ullT cw = cmR[wstT];
                ullT coA = 0, cwA = 0;
                if (tr > 0) { coA = cmL[ownT - 8]; cwA = cmR[wstT - 8]; }
                int r = lane;
                if ((co >> r) & 1ULL) {
                    bool W  = (cw >> r) & 1ULL;
                    bool pO = r ? ((co >> (r - 1)) & 1ULL) : ((coA >> 63) & 1ULL);
                    bool pW = r ? ((cw >> (r - 1)) & 1ULL) : ((cwA >> 63) & 1ULL);
                    int i = (((tr << 6) + r) << 9) + c;
                    if (r == 0) {   // conservative at tile-top (breaks skip cycle)
                        if (W) uniteS(par, S[i] - 1, S[i - 1] - 1);
                        else if (pW) uniteS(par, S[i] - 1, S[i - WW - 1] - 1);
                    } else {
                        if (W) { if (!(pO && pW)) uniteS(par, S[i] - 1, S[i - 1] - 1); }
                        else if (pW && !pO) uniteS(par, S[i] - 1, S[i - WW - 1] - 1);
                    }
                }
            } else {                // NE edges at c=64q+63, tile-row t8
                int c = (q << 6) + 63, tr = t8;
                int ownT = (b << 6) + (tr << 3) + q;
                int estT = ownT + 1;
                ullT co = cmR[ownT];
                if (!co) continue;
                ullT ce = cmL[estT];
                ullT coA = 0, ceA = 0;
                if (tr > 0) { coA = cmR[ownT - 8]; ceA = cmL[estT - 8]; }
                int r = lane;
                if ((co >> r) & 1ULL) {
                    bool E  = (ce >> r) & 1ULL;
                    bool NE = r ? ((ce >> (r - 1)) & 1ULL) : ((ceA >> 63) & 1ULL);
                    bool pO = r ? ((co >> (r - 1)) & 1ULL) : false;   // conservative at r=0
                    if (NE && !E && !pO) {
                        int i = (((tr << 6) + r) << 9) + c;
                        uniteS(par, S[i] - 1, S[i - WW + 1] - 1);
                    }
                }
            }
        }
    }
    __syncthreads();

    // A: filter root slots + sort their pixel keys, build compact tables
    for (int side = 0; side < 2; side++) {
        const int* par = parL[side];
        int n = min((side ? candCntG : candCntP)[b], CCAP);
        if (tid == 0) lcnt = 0;
        __syncthreads();
        for (int t = tid; t < n; t += 512) {
            int pk = par[t];
            if ((pk & (CCAP - 1)) == t) { int pos = atomicAdd(&lcnt, 1); if (pos < RCAP) s[pos] = pk >> 12; }
        }
        __syncthreads();
        int nn2 = min(lcnt, RCAP);
        int m = 1; while (m < nn2) m <<= 1;
        for (int t = nn2 + tid; t < m; t += 512) s[t] = IMAX;
        __syncthreads();
        for (int k = 2; k <= m; k <<= 1) {
            for (int j = k >> 1; j > 0; j >>= 1) {
                for (int t = tid; t < m; t += 512) {
                    int ixj = t ^ j;
                    if (ixj > t) {
                        int a = s[t], bb = s[ixj];
                        bool up = ((t & k) == 0);
                        if ((a > bb) == up) { s[t] = bb; s[ixj] = a; }
                    }
                }
                __syncthreads();
            }
        }
        int cc = min(nn2, KC);
        for (int t = tid; t < KC; t += 512)
            compL[side][t] = (t < cc) ? s[t] : IMAX;
        if (tid == 0) { ccX[side] = cc; if (side) ccntG_g[b] = cc; }
        __syncthreads();
    }

    // B: zero LDS cid stats
    for (int t = tid; t < KC; t += 512) {
        stA[0][t] = 0; stR[0][t] = 0; stC[0][t] = 0; stOv[0][t] = 0;
        stA[1][t] = 0; stR[1][t] = 0; stC[1][t] = 0; stOv[1][t] = 0;
    }
    __syncthreads();

    // C: per-slot chase (LDS forest) + bsearch + aggregate
    short* cidS = (short*)s;
    for (int side = 0; side < 2; side++) {
        const int* par = parL[side];
        const int* aA = side ? sAreaG : sAreaP;
        const int* aR = side ? sRG : sRP;
        const int* aC = side ? sCG : sCP;
        const int* aO = side ? sOvG : sOvP;
        int n = min((side ? candCntG : candCntP)[b], CCAP);
        for (int slot = tid; slot < n; slot += 512) {
            int pk = rootPk(par, slot);
            int cid = bsearch_k(compL[side], pk >> 12);
            cidS[side * CCAP + slot] = (short)cid;
            if (cid >= 0) {
                int sidx = b * CCAP + slot;
                atomicAdd(&stA[side][cid], aA[sidx]);
                atomicAdd(&stR[side][cid], aR[sidx]);
                atomicAdd(&stC[side][cid], aC[sidx]);
                if (aO[sidx]) atomicOr(&stOv[side][cid], 1);
            }
        }
    }
    __syncthreads();

    // D: nearest gt centroid per pred region, region errors
    int t = tid;                                   // 512 == KC
    int ccg = ccX[1], ccp = ccX[0];
    {
        float fa = (float)stA[1][t];
        float d = fmaxf(fa, 1.0f);
        gAf[t] = fa;
        gRf[t] = (float)stR[1][t] / d;
        gCf[t] = (float)stC[1][t] / d;
        sEG[t] = 0.0f;
    }
    __syncthreads();
    float e_eff = 0.0f;
    int nn = 0;
    if (t < ccp) {
        float pa = (float)stA[0][t];
        float dd = fmaxf(pa, 1.0f);
        float pcr = (float)stR[0][t] / dd;
        float pcc = (float)stC[0][t] / dd;
        float best = INFINITY;
        for (int gi = 0; gi < ccg; gi++) {
            float dr = pcr - gRf[gi], dc = pcc - gCf[gi];
            float d2 = dr * dr + dc * dc;
            if (d2 < best) { best = d2; nn = gi; }  // first-min ties like argmin
        }
        if (ccg > 0 && stOv[0][t]) {
            float ratio = 1.0f - gAf[nn] / dd;
            e_eff = fminf(fabsf(1.0f - __expf(ratio)), 1.0f);
        }
    }
    if (e_eff > 0.0f) atomicMax((int*)&sEG[nn], __float_as_int(e_eff));
    sFPl[t] = stOv[0][t] ? e_eff : -1.0f;
    __syncthreads();
    sFGl[t] = stOv[1][t] ? fmaxf(sEG[t], 0.0f) : -1.0f;
    __syncthreads();

    // E: scatter per-slot value tables
    int nP = min(candCntP[b], CCAP), nG = min(candCntG[b], CCAP);
    for (int s2 = tid; s2 < nP; s2 += 512) {
        int cid = cidS[s2];
        vPs[b * CCAP + s2] = (cid >= 0) ? sFPl[cid] : -3.0f;   // -3 = fg w/o compact id
    }
    for (int s2 = tid; s2 < nG; s2 += 512) {
        int cid = cidS[CCAP + s2];
        vGs[b * CCAP + s2] = (cid >= 0) ? sFGl[cid] : 0.0f;
    }
}

// per-pixel error rules + fused loss/metric reduction: pure table lookups.
// 2 pixels per thread; per-block PARTIAL STORES (no global atomics).
__global__ __launch_bounds__(TPB) void k_final(const float* __restrict__ in,
                        const ushortT* __restrict__ slotP, const ushortT* __restrict__ slotG,
                        const float* __restrict__ vPs, const float* __restrict__ vGs,
                        const int* __restrict__ ccntG,
                        double* __restrict__ partLm, double* __restrict__ partPe,
                        double* __restrict__ partCnt) {
    __shared__ float pLm[4], pPe[4];
    __shared__ int pCnt[4];
    const uintT* sp2 = (const uintT*)slotP;
    const uintT* sg2 = (const uintT*)slotG;
    const float2* in2 = (const float2*)in;
    int b = blockIdx.x >> 6;            // 64 blocks per image, 2048 pairs each
    int blk = blockIdx.x & 63;
    bool hasGt = ccntG[b] > 0;
    const float* vP = vPs + b * CCAP;
    const float* vG = vGs + b * CCAP;
    float aLm = 0.0f, aPe = 0.0f;
    int aCnt = 0;
    #pragma unroll
    for (int k = 0; k < 8; k++) {
        int pidx = (b << 17) + (blk << 11) + (k << 8) + threadIdx.x;
        uintT up = sp2[pidx], ug = sg2[pidx];
        if (!__any(up | ug)) continue;   // whole wave background
        float pe0 = 0.0f, pe1 = 0.0f;
        {
            int fp = up & 0xffff, fg = ug & 0xffff;
            if (fp) {
                if (!hasGt) pe0 = 1.0f;
                else {
                    float v = vP[fp - 1];
                    if (v > -2.5f) { if (v < 0.0f) pe0 = 1.0f; else if (!fg) pe0 = v; }
                }
            }
            if (fg) {
                float vg = vG[fg - 1];
                if (!fp) pe0 = fmaxf(pe0, fmaxf(vg, 0.0f));
                if (vg < 0.0f) pe0 = 1.0f;
            }
        }
        {
            int fp = up >> 16, fg = ug >> 16;
            if (fp) {
                if (!hasGt) pe1 = 1.0f;
                else {
                    float v = vP[fp - 1];
                    if (v > -2.5f) { if (v < 0.0f) pe1 = 1.0f; else if (!fg) pe1 = v; }
                }
            }
            if (fg) {
                float vg = vG[fg - 1];
                if (!fp) pe1 = fmaxf(pe1, fmaxf(vg, 0.0f));
                if (vg < 0.0f) pe1 = 1.0f;
            }
        }
        if (pe0 != 0.0f || pe1 != 0.0f) {
            float2 x2 = in2[pidx];
            if (pe0 != 0.0f) {
                float score = 1.0f / (1.0f + __expf(-x2.x));
                aLm += (1.0f / (1.0f + __expf(-(score + 1.0f) * pe0)) - 0.5f) * 2.0f;
                aPe += pe0; aCnt++;
            }
            if (pe1 != 0.0f) {
                float score = 1.0f / (1.0f + __expf(-x2.y));
                aLm += (1.0f / (1.0f + __expf(-(score + 1.0f) * pe1)) - 0.5f) * 2.0f;
                aPe += pe1; aCnt++;
            }
        }
    }
    for (int o = 32; o; o >>= 1) {
        aLm += __shfl_xor(aLm, o);
        aPe += __shfl_xor(aPe, o);
        aCnt += __shfl_xor(aCnt, o);
    }
    int wv = threadIdx.x >> 6, lane = threadIdx.x & 63;
    if (lane == 0) { pLm[wv] = aLm; pPe[wv] = aPe; pCnt[wv] = aCnt; }
    __syncthreads();
    if (threadIdx.x == 0) {
        double sl = 0, sp = 0; int sc = 0;
        for (int q = 0; q < 4; q++) { sl += pLm[q]; sp += pPe[q]; sc += pCnt[q]; }
        partLm[blockIdx.x] = sl;
        partPe[blockIdx.x] = sp;
        partCnt[blockIdx.x] = (double)sc;
    }
}

// single-block reduction of the per-block partials -> 3 outputs
__global__ __launch_bounds__(TPB) void k_out(const double* __restrict__ partLm,
                                             const double* __restrict__ partPe,
                                             const double* __restrict__ partCnt,
                                             float* __restrict__ out) {
    __shared__ double r0[TPB], r1[TPB], r2[TPB];
    double sl = 0, sp = 0, sc = 0;
    for (int i = threadIdx.x; i < NFIN; i += TPB) {
        sl += partLm[i]; sp += partPe[i]; sc += partCnt[i];
    }
    r0[threadIdx.x] = sl; r1[threadIdx.x] = sp; r2[threadIdx.x] = sc;
    __syncthreads();
    for (int s = TPB >> 1; s > 0; s >>= 1) {
        if (threadIdx.x < s) {
            r0[threadIdx.x] += r0[threadIdx.x + s];
            r1[threadIdx.x] += r1[threadIdx.x + s];
            r2[threadIdx.x] += r2[threadIdx.x + s];
        }
        __syncthreads();
    }
    if (threadIdx.x == 0) {
        out[0] = (float)(r0[0] / (double)PN);
        out[1] = (float)(1.0 - r1[0] / (double)PN);
        out[2] = (float)(1.0 - r1[0] / r2[0]);
    }
}

extern "C" void kernel_launch(void* const* d_in, const int* in_sizes, int n_in,
                              void* d_out, int out_size, void* d_ws, size_t ws_size,
                              hipStream_t stream) {
    const float* in = (const float*)d_in[0];
    const float* tg = (const float*)d_in[1];
    // d_in[2] = epoch, unused by forward

    char* w = (char*)d_ws;
    size_t off = 0;
    ullT* rmP = (ullT*)(w + off); off += (size_t)(PN / 64) * 8;
    ullT* rmG = (ullT*)(w + off); off += (size_t)(PN / 64) * 8;
    ushortT* slotP = (ushortT*)(w + off); off += (size_t)PN * 2;
    ushortT* slotG = (ushortT*)(w + off); off += (size_t)PN * 2;
    int* parP = (int*)(w + off); off += (size_t)NB * CCAP * 4;
    int* parG = (int*)(w + off); off += (size_t)NB * CCAP * 4;
    ullT* cmLP = (ullT*)(w + off); off += (size_t)NB * 64 * 8;
    ullT* cmRP = (ullT*)(w + off); off += (size_t)NB * 64 * 8;
    ullT* cmLG = (ullT*)(w + off); off += (size_t)NB * 64 * 8;
    ullT* cmRG = (ullT*)(w + off); off += (size_t)NB * 64 * 8;
    float* vPs = (float*)(w + off); off += (size_t)NB * CCAP * 4;
    float* vGs = (float*)(w + off); off += (size_t)NB * CCAP * 4;
    int* ccntG = (int*)(w + off); off += NB * 4;
    double* partLm = (double*)(w + off); off += (size_t)NFIN * 8;
    double* partPe = (double*)(w + off); off += (size_t)NFIN * 8;
    double* partCnt = (double*)(w + off); off += (size_t)NFIN * 8;
    size_t zoff = off;
    int* candCntP = (int*)(w + off); off += NB * 4;
    int* candCntG = (int*)(w + off); off += NB * 4;
    int* sAreaP = (int*)(w + off); off += (size_t)NB * CCAP * 4;
    int* sRP    = (int*)(w + off); off += (size_t)NB * CCAP * 4;
    int* sCP    = (int*)(w + off); off += (size_t)NB * CCAP * 4;
    int* sOvP   = (int*)(w + off); off += (size_t)NB * CCAP * 4;
    int* sAreaG = (int*)(w + off); off += (size_t)NB * CCAP * 4;
    int* sRG    = (int*)(w + off); off += (size_t)NB * CCAP * 4;
    int* sCG    = (int*)(w + off); off += (size_t)NB * CCAP * 4;
    int* sOvG   = (int*)(w + off); off += (size_t)NB * CCAP * 4;
    size_t zend = off;

    // zero counters + slot stats (fresh every call)
    hipMemsetAsync(w + zoff, 0, zend - zoff, stream);

    k_prep<<<2048, TPB, 0, stream>>>(in, tg, rmP, rmG);
    k_local<<<NB * 64 * 2, TPB, 0, stream>>>(rmP, rmG, slotP, slotG, parP, parG,
                                             cmLP, cmRP, cmLG, cmRG,
                                             candCntP, candCntG,
                                             sAreaP, sRP, sCP, sOvP,
                                             sAreaG, sRG, sCG, sOvG);
    k_post<<<NB, 512, 0, stream>>>(rmP, rmG, cmLP, cmRP, cmLG, cmRG,
                                   slotP, slotG, parP, parG,
                                   candCntP, candCntG,
                                   sAreaP, sRP, sCP, sOvP,
                                   sAreaG, sRG, sCG, sOvG,
                                   ccntG, vPs, vGs);
    k_final<<<NFIN, TPB, 0, stream>>>(in, slotP, slotG, vPs, vGs, ccntG,
                                      partLm, partPe, partCnt);
    k_out<<<1, TPB, 0, stream>>>(partLm, partPe, partCnt, (float*)d_out);
}

// Round 18
// 134.172 us; speedup vs baseline: 1.3238x; 1.2012x over previous
//
#include <hip/hip_runtime.h>

#define NB 16
#define HH 512
#define WW 512
#define HWN (HH * WW)            // 262144 = 1<<18
#define KC 512                    // max regions kept per image
#define RCAP 4096                 // root list capacity per image
#define CCAP 4096                 // tile-root slot capacity per image
#define PN (NB * HWN)
#define TPB 256
#define IMAX 0x7FFFFFFF
#define TS 64                     // CCL tile side
#define TSQ (TS * TS)             // 4096, local sentinel
#define NFIN (NB * 128)           // k_final grid (2048 blocks)

typedef unsigned short ushortT;
typedef unsigned int uintT;
typedef unsigned long long ullT;

// ---------------- union-find helpers (LDS, pixel-in-tile) ----------------
__device__ __forceinline__ int findRootL(int* s, int i) {
    int p = s[i];
    while (p != i) { i = p; p = s[i]; }
    return i;
}

__device__ __forceinline__ void uniteL(int* s, int a, int b) {
    int ra = findRootL(s, a);
    int rb = findRootL(s, b);
    while (ra != rb) {
        int lo = min(ra, rb), hi = max(ra, rb);
        int old = atomicMin(&s[hi], lo);
        if (old == hi) return;
        ra = old; rb = lo;
    }
}

// ---------------- union-find (global, slot space, packed key<<12|slot) ----
// Monotone atomicMin: parent entries only decrease; min-key root wins.
__device__ __forceinline__ int rootPk(const int* __restrict__ par, int s) {
    int q = par[s];
    while ((q & (CCAP - 1)) != s) { s = q & (CCAP - 1); q = par[s]; }
    return q;                      // packed (key<<12|slot) of root
}

__device__ __forceinline__ void uniteS(int* par, int a, int b) {
    int pa = rootPk(par, a);
    int pb = rootPk(par, b);
    while (pa != pb) {
        int lo = min(pa, pb), hi = max(pa, pb);
        int hs = hi & (CCAP - 1);
        int old = atomicMin(&par[hs], lo);
        if (old == hi) return;
        pa = rootPk(par, old & (CCAP - 1));
        pb = rootPk(par, lo & (CCAP - 1));
    }
}

// binary search exact key in ascending array of KC ints (padded IMAX)
__device__ __forceinline__ int bsearch_k(const int* a, int key) {
    int lo = 0, hi = KC;
    while (lo < hi) { int m = (lo + hi) >> 1; if (a[m] < key) lo = m + 1; else hi = m; }
    return (lo < KC && a[lo] == key) ? lo : -1;
}

// ---------------- kernels ----------------
// Streaming prepass (float4-vectorized): threshold both masks, assemble
// 64-bit row-chunk masks via 16-lane shfl-OR reduction.
// Layout: rm[((tc*NB + b) << 9) + r]  (tc = column chunk 0..7).
__global__ __launch_bounds__(TPB) void k_prep(const float* __restrict__ in, const float* __restrict__ tg,
                                              ullT* __restrict__ rmP, ullT* __restrict__ rmG) {
    int lane = threadIdx.x & 63;
    int wid = (blockIdx.x * blockDim.x + threadIdx.x) >> 6;   // 8192 waves
    const float4* in4 = (const float4*)in;
    const float4* tg4 = (const float4*)tg;
    #pragma unroll
    for (int it = 0; it < 2; it++) {
        int span = wid + (it << 13);          // 16384 spans of 256 px
        int vidx = (span << 6) + lane;        // float4 index
        float4 a = in4[vidx];
        float4 t4 = tg4[vidx];
        uintT bp = (a.x > 0.0f) | ((a.y > 0.0f) << 1) | ((a.z > 0.0f) << 2) | ((a.w > 0.0f) << 3);
        uintT bg = (t4.x > 0.5f) | ((t4.y > 0.5f) << 1) | ((t4.z > 0.5f) << 2) | ((t4.w > 0.5f) << 3);
        ullT vp = (ullT)bp << ((lane & 15) << 2);
        ullT vg = (ullT)bg << ((lane & 15) << 2);
        #pragma unroll
        for (int o = 1; o < 16; o <<= 1) {
            vp |= __shfl_xor(vp, o);
            vg |= __shfl_xor(vg, o);
        }
        if ((lane & 15) == 0) {
            int g = (span << 8) + ((lane >> 4) << 6);
            int b = g >> 18, r = (g >> 9) & 511, tc = (g >> 6) & 7;
            int idx = (((tc << 4) + b) << 9) + r;
            rmP[idx] = vp; rmG[idx] = vg;
        }
    }
}

// Per-(tile,mask) CCL from row masks (round-13 version; stats self-zeroed).
__global__ __launch_bounds__(TPB) void k_local(const ullT* __restrict__ rmPArr, const ullT* __restrict__ rmGArr,
                        ushortT* __restrict__ slotP, ushortT* __restrict__ slotG,
                        int* __restrict__ parP, int* __restrict__ parG,
                        ullT* __restrict__ cmLP, ullT* __restrict__ cmRP,
                        ullT* __restrict__ cmLG, ullT* __restrict__ cmRG,
                        int* __restrict__ candCntP, int* __restrict__ candCntG,
                        int* __restrict__ sAreaP, int* __restrict__ sRP, int* __restrict__ sCP, int* __restrict__ sOvP,
                        int* __restrict__ sAreaG, int* __restrict__ sRG, int* __restrict__ sCG, int* __restrict__ sOvG) {
    __shared__ int s[TSQ];
    __shared__ ullT rm[TS], rmO[TS];
    int side = blockIdx.x & 1;
    int tileIdx = blockIdx.x >> 1;
    int b = tileIdx >> 6;               // 64 tiles per image (8x8)
    int tile = tileIdx & 63;
    int r0 = (tile >> 3) << 6, c0 = (tile & 7) << 6;
    int tc = tile & 7;
    int base = (b << 18) + (r0 << 9) + c0;
    int wv = threadIdx.x >> 6, lane = threadIdx.x & 63;

    const ullT* own = side ? rmGArr : rmPArr;
    const ullT* oth = side ? rmPArr : rmGArr;
    ushortT* slotArr = side ? slotG : slotP;
    int* par  = side ? parG : parP;
    ullT* cmLo = side ? cmLG : cmLP;
    ullT* cmRo = side ? cmRG : cmRP;
    int* candCnt = side ? candCntG : candCntP;
    int* sArea = side ? sAreaG : sAreaP;
    int* sR = side ? sRG : sRP;
    int* sC = side ? sCG : sCP;
    int* sOv = side ? sOvG : sOvP;

    // phase 0: load 64+64 row masks (512B each, contiguous)
    int rowIdx = (((tc << 4) + b) << 9) + r0;
    if (threadIdx.x < 64) rm[threadIdx.x] = own[rowIdx + threadIdx.x];
    else if (threadIdx.x < 128) rmO[threadIdx.x - 64] = oth[rowIdx + threadIdx.x - 64];
    __syncthreads();

    // phase 0b: export edge-column masks (wave 0: lane = row)
    if (threadIdx.x < 64) {
        ullT v = rm[threadIdx.x];
        ullT mL = __ballot((v & 1ULL) != 0);
        ullT mR = __ballot((v >> 63) != 0);
        if (threadIdx.x == 0) { cmLo[tileIdx] = mL; cmRo[tileIdx] = mR; }
    }

    // phase 1: run-start initial labels (no atomics, no ballots)
    #pragma unroll
    for (int k = 0; k < 16; k++) {
        int lr = wv + (k << 2);
        ullT mp = rm[lr];
        bool p = (mp >> lane) & 1ULL;
        int t = (lr << 6) + lane;
        ullT below = (lane == 0) ? 0ULL : ((~mp) & ((1ULL << lane) - 1ULL));
        int st = below ? (64 - __clzll(below)) : 0;
        s[t] = p ? ((lr << 6) + st) : TSQ;
    }
    __syncthreads();

    // phase 2: inter-row unions, reduced rules
    for (int lr = wv; lr < TS; lr += 4) {
        if (lr == 0) continue;
        int t = (lr << 6) + lane;
        ullT m = rm[lr], a = rm[lr - 1];
        if ((m >> lane) & 1ULL) {
            bool N  = (a >> lane) & 1ULL;
            bool W  = lane > 0  && ((m >> (lane - 1)) & 1ULL);
            bool NW = lane > 0  && ((a >> (lane - 1)) & 1ULL);
            bool E  = lane < 63 && ((m >> (lane + 1)) & 1ULL);
            bool NE = lane < 63 && ((a >> (lane + 1)) & 1ULL);
            if (N) { if (!(W && NW)) uniteL(s, t, t - TS); }
            else {
                if (NW && !W) uniteL(s, t, t - TS - 1);
                if (NE && !E) uniteL(s, t, t - TS + 1);
            }
        }
    }
    __syncthreads();

    // phase 3a: full path compression (racy-but-monotone, safe)
    #pragma unroll
    for (int k = 0; k < 16; k++) {
        int t = ((wv + (k << 2)) << 6) + lane;
        if (s[t] < TSQ) s[t] = findRootL(s, t);
    }
    __syncthreads();

    // phase 3b: roots -> slots (encode negative), packed par init,
    // stats self-zero (slot stats are only touched by this block).
    #pragma unroll
    for (int k = 0; k < 16; k++) {
        int t = ((wv + (k << 2)) << 6) + lane;
        if (s[t] == t) {
            int pos = atomicAdd(&candCnt[b], 1);
            if (pos >= CCAP) pos = CCAP - 1;
            int gl = ((r0 + (t >> 6)) << 9) + (c0 + (t & 63));
            par[b * CCAP + pos] = (gl << 12) | pos;
            sArea[b * CCAP + pos] = 0;
            sR[b * CCAP + pos] = 0;
            sC[b * CCAP + pos] = 0;
            sOv[b * CCAP + pos] = 0;
            s[t] = -(pos + 2);
        }
    }
    __syncthreads();

    // phase 3c: per-pixel slot write + per-run stats
    #pragma unroll
    for (int k = 0; k < 16; k++) {
        int lr = wv + (k << 2);
        int t = (lr << 6) + lane;
        int g = base + (lr << 9) + lane;
        int vp = s[t];
        int slot = 0;
        if (vp != TSQ) slot = (vp < 0) ? (-vp - 1) : (-s[vp] - 1);
        slotArr[g] = (ushortT)slot;
        // run stats (run-start lanes only)
        ullT mp = rm[lr], mq = rmO[lr];
        bool isF = (mp >> lane) & 1ULL;
        if (isF && (lane == 0 || !((mp >> (lane - 1)) & 1ULL))) {
            ullT x = ~(mp >> lane);
            int len = x ? (__ffsll((long long)x) - 1) : (64 - lane);
            int sl = slot - 1;
            ullT runbits = (len >= 64) ? ~0ULL : (((1ULL << len) - 1ULL) << lane);
            atomicAdd(&sArea[b * CCAP + sl], len);
            atomicAdd(&sR[b * CCAP + sl], (r0 + lr) * len);
            atomicAdd(&sC[b * CCAP + sl], len * (c0 + lane) + (len * (len - 1)) / 2);
            if (mq & runbits) atomicOr(&sOv[b * CCAP + sl], 1);
        }
    }
}

// Mask-driven cross-tile merges. One wave per (image, type, q, t8); only
// union-firing lanes touch the slot arrays.
__global__ __launch_bounds__(TPB) void k_bmerge(
        const ullT* __restrict__ rmP, const ullT* __restrict__ rmG,
        const ullT* __restrict__ cmLP, const ullT* __restrict__ cmRP,
        const ullT* __restrict__ cmLG, const ullT* __restrict__ cmRG,
        const ushortT* __restrict__ slotP, const ushortT* __restrict__ slotG,
        int* __restrict__ parP, int* __restrict__ parG) {
    int wid = (blockIdx.x << 2) + (threadIdx.x >> 6);   // 2688 waves
    int lane = threadIdx.x & 63;
    int b = wid / 168;
    int rem = wid % 168;
    int type = rem / 56;
    int sub = rem % 56;
    int q = sub >> 3, t8 = sub & 7;

    for (int side = 0; side < 2; side++) {
        const ullT* rm = side ? rmG : rmP;
        const ullT* cmL = side ? cmLG : cmLP;
        const ullT* cmR = side ? cmRG : cmRP;
        const ushortT* S = (side ? slotG : slotP) + (b << 18);
        int* par = (side ? parG : parP) + b * CCAP;

        if (type == 0) {
            int r = (q + 1) << 6, tc = t8;
            int ib = (((tc << 4) + b) << 9);
            ullT m = rm[ib + r];
            if (!m) continue;
            ullT a = rm[ib + r - 1];
            ullT mW = 0, aW = 0, mE = 0, aE = 0;
            if (tc > 0) { int iw = ((((tc - 1) << 4) + b) << 9); mW = rm[iw + r]; aW = rm[iw + r - 1]; }
            if (tc < 7) { int ie = ((((tc + 1) << 4) + b) << 9); mE = rm[ie + r]; aE = rm[ie + r - 1]; }
            if ((m >> lane) & 1ULL) {
                bool N  = (a >> lane) & 1ULL;
                bool W  = lane ? ((m >> (lane - 1)) & 1ULL) : ((mW >> 63) & 1ULL);
                bool NW = lane ? ((a >> (lane - 1)) & 1ULL) : ((aW >> 63) & 1ULL);
                bool E  = (lane < 63) ? ((m >> (lane + 1)) & 1ULL) : (mE & 1ULL);
                bool NE = (lane < 63) ? ((a >> (lane + 1)) & 1ULL) : (aE & 1ULL);
                int i = (r << 9) + (tc << 6) + lane;
                if (N) {
                    if (!(W && NW)) uniteS(par, S[i] - 1, S[i - WW] - 1);
                } else {
                    if (NW && !W) uniteS(par, S[i] - 1, S[i - WW - 1] - 1);
                    if (NE && !E) uniteS(par, S[i] - 1, S[i - WW + 1] - 1);
                }
            }
        } else if (type == 1) {
            int c = (q + 1) << 6, tr = t8;
            int ownT = (b << 6) + (tr << 3) + (q + 1);
            int wstT = ownT - 1;
            ullT co = cmL[ownT];
            if (!co) continue;
            ullT cw = cmR[wstT];
            ullT coA = 0, cwA = 0;
            if (tr > 0) { coA = cmL[ownT - 8]; cwA = cmR[wstT - 8]; }
            int r = lane;
            if ((co >> r) & 1ULL) {
                bool W  = (cw >> r) & 1ULL;
                bool pO = r ? ((co >> (r - 1)) & 1ULL) : ((coA >> 63) & 1ULL);
                bool pW = r ? ((cw >> (r - 1)) & 1ULL) : ((cwA >> 63) & 1ULL);
                int i = (((tr << 6) + r) << 9) + c;
                if (r == 0) {   // conservative at tile-top (breaks skip cycle)
                    if (W) uniteS(par, S[i] - 1, S[i - 1] - 1);
                    else if (pW) uniteS(par, S[i] - 1, S[i - WW - 1] - 1);
                } else {
                    if (W) { if (!(pO && pW)) uniteS(par, S[i] - 1, S[i - 1] - 1); }
                    else if (pW && !pO) uniteS(par, S[i] - 1, S[i - WW - 1] - 1);
                }
            }
        } else {
            int c = (q << 6) + 63, tr = t8;
            int ownT = (b << 6) + (tr << 3) + q;
            int estT = ownT + 1;
            ullT co = cmR[ownT];
            if (!co) continue;
            ullT ce = cmL[estT];
            ullT coA = 0, ceA = 0;
            if (tr > 0) { coA = cmR[ownT - 8]; ceA = cmL[estT - 8]; }
            int r = lane;
            if ((co >> r) & 1ULL) {
                bool E  = (ce >> r) & 1ULL;
                bool NE = r ? ((ce >> (r - 1)) & 1ULL) : ((ceA >> 63) & 1ULL);
                bool pO = r ? ((co >> (r - 1)) & 1ULL) : false;   // conservative at r=0
                if (NE && !E && !pO) {
                    int i = (((tr << 6) + r) << 9) + c;
                    uniteS(par, S[i] - 1, S[i - WW + 1] - 1);
                }
            }
        }
    }
}

// One block per IMAGE (512 thr): filter+sort root keys (both masks), slot->cid
// redux with LDS stats, centroid match, scatter per-slot value tables.
__global__ __launch_bounds__(512) void k_post(
        const int* __restrict__ parP, const int* __restrict__ parG,
        const int* __restrict__ candCntP, const int* __restrict__ candCntG,
        const int* __restrict__ sAreaP, const int* __restrict__ sRP, const int* __restrict__ sCP, const int* __restrict__ sOvP,
        const int* __restrict__ sAreaG, const int* __restrict__ sRG, const int* __restrict__ sCG, const int* __restrict__ sOvG,
        int* __restrict__ ccntG_g, float* __restrict__ vPs, float* __restrict__ vGs) {
    __shared__ int s[RCAP];                       // sort buffer, later cid store
    __shared__ int compL[2][KC];
    __shared__ int stA[2][KC], stR[2][KC], stC[2][KC], stOv[2][KC];
    __shared__ float gAf[KC], gRf[KC], gCf[KC], sEG[KC], sFPl[KC], sFGl[KC];
    __shared__ int lcnt, ccX[2];
    int b = blockIdx.x;
    int tid = threadIdx.x;

    // A: filter root slots + sort their pixel keys, build compact tables
    for (int side = 0; side < 2; side++) {
        const int* par = (side ? parG : parP) + b * CCAP;
        int n = min((side ? candCntG : candCntP)[b], CCAP);
        if (tid == 0) lcnt = 0;
        __syncthreads();
        for (int t = tid; t < n; t += 512) {
            int pk = par[t];
            if ((pk & (CCAP - 1)) == t) { int pos = atomicAdd(&lcnt, 1); if (pos < RCAP) s[pos] = pk >> 12; }
        }
        __syncthreads();
        int nn2 = min(lcnt, RCAP);
        int m = 1; while (m < nn2) m <<= 1;
        for (int t = nn2 + tid; t < m; t += 512) s[t] = IMAX;
        __syncthreads();
        for (int k = 2; k <= m; k <<= 1) {
            for (int j = k >> 1; j > 0; j >>= 1) {
                for (int t = tid; t < m; t += 512) {
                    int ixj = t ^ j;
                    if (ixj > t) {
                        int a = s[t], bb = s[ixj];
                        bool up = ((t & k) == 0);
                        if ((a > bb) == up) { s[t] = bb; s[ixj] = a; }
                    }
                }
                __syncthreads();
            }
        }
        int cc = min(nn2, KC);
        for (int t = tid; t < KC; t += 512)
            compL[side][t] = (t < cc) ? s[t] : IMAX;
        if (tid == 0) { ccX[side] = cc; if (side) ccntG_g[b] = cc; }
        __syncthreads();
    }

    // B: zero LDS cid stats
    for (int t = tid; t < KC; t += 512) {
        stA[0][t] = 0; stR[0][t] = 0; stC[0][t] = 0; stOv[0][t] = 0;
        stA[1][t] = 0; stR[1][t] = 0; stC[1][t] = 0; stOv[1][t] = 0;
    }
    __syncthreads();

    // C: per-slot chase (packed forest, L2-hot) + bsearch + aggregate
    short* cidS = (short*)s;
    for (int side = 0; side < 2; side++) {
        const int* par = (side ? parG : parP) + b * CCAP;
        const int* aA = side ? sAreaG : sAreaP;
        const int* aR = side ? sRG : sRP;
        const int* aC = side ? sCG : sCP;
        const int* aO = side ? sOvG : sOvP;
        int n = min((side ? candCntG : candCntP)[b], CCAP);
        for (int slot = tid; slot < n; slot += 512) {
            int pk = rootPk(par, slot);
            int cid = bsearch_k(compL[side], pk >> 12);
            cidS[side * CCAP + slot] = (short)cid;
            if (cid >= 0) {
                int sidx = b * CCAP + slot;
                atomicAdd(&stA[side][cid], aA[sidx]);
                atomicAdd(&stR[side][cid], aR[sidx]);
                atomicAdd(&stC[side][cid], aC[sidx]);
                if (aO[sidx]) atomicOr(&stOv[side][cid], 1);
            }
        }
    }
    __syncthreads();

    // D: nearest gt centroid per pred region, region errors
    int t = tid;                                   // 512 == KC
    int ccg = ccX[1], ccp = ccX[0];
    {
        float fa = (float)stA[1][t];
        float d = fmaxf(fa, 1.0f);
        gAf[t] = fa;
        gRf[t] = (float)stR[1][t] / d;
        gCf[t] = (float)stC[1][t] / d;
        sEG[t] = 0.0f;
    }
    __syncthreads();
    float e_eff = 0.0f;
    int nn = 0;
    if (t < ccp) {
        float pa = (float)stA[0][t];
        float dd = fmaxf(pa, 1.0f);
        float pcr = (float)stR[0][t] / dd;
        float pcc = (float)stC[0][t] / dd;
        float best = INFINITY;
        for (int gi = 0; gi < ccg; gi++) {
            float dr = pcr - gRf[gi], dc = pcc - gCf[gi];
            float d2 = dr * dr + dc * dc;
            if (d2 < best) { best = d2; nn = gi; }  // first-min ties like argmin
        }
        if (ccg > 0 && stOv[0][t]) {
            float ratio = 1.0f - gAf[nn] / dd;
            e_eff = fminf(fabsf(1.0f - __expf(ratio)), 1.0f);
        }
    }
    if (e_eff > 0.0f) atomicMax((int*)&sEG[nn], __float_as_int(e_eff));
    sFPl[t] = stOv[0][t] ? e_eff : -1.0f;
    __syncthreads();
    sFGl[t] = stOv[1][t] ? fmaxf(sEG[t], 0.0f) : -1.0f;
    __syncthreads();

    // E: scatter per-slot value tables
    int nP = min(candCntP[b], CCAP), nG = min(candCntG[b], CCAP);
    for (int s2 = tid; s2 < nP; s2 += 512) {
        int cid = cidS[s2];
        vPs[b * CCAP + s2] = (cid >= 0) ? sFPl[cid] : -3.0f;   // -3 = fg w/o compact id
    }
    for (int s2 = tid; s2 < nG; s2 += 512) {
        int cid = cidS[CCAP + s2];
        vGs[b * CCAP + s2] = (cid >= 0) ? sFGl[cid] : 0.0f;
    }
}

// per-pixel error rules + fused loss/metric reduction: pure table lookups.
// 2 pixels per thread; batched register loads; per-block partial stores.
__global__ __launch_bounds__(TPB) void k_final(const float* __restrict__ in,
                        const ushortT* __restrict__ slotP, const ushortT* __restrict__ slotG,
                        const float* __restrict__ vPs, const float* __restrict__ vGs,
                        const int* __restrict__ ccntG,
                        double* __restrict__ partLm, double* __restrict__ partPe,
                        double* __restrict__ partCnt) {
    __shared__ float pLm[4], pPe[4];
    __shared__ int pCnt[4];
    const uintT* sp2 = (const uintT*)slotP;
    const uintT* sg2 = (const uintT*)slotG;
    const float2* in2 = (const float2*)in;
    int b = blockIdx.x >> 7;            // 128 blocks per image, 1024 pairs each
    int blk = blockIdx.x & 127;
    bool hasGt = ccntG[b] > 0;
    const float* vP = vPs + b * CCAP;
    const float* vG = vGs + b * CCAP;
    int i0 = (b << 17) + (blk << 10) + threadIdx.x;
    // batched loads: 8 independent loads in flight
    uintT upv[4], ugv[4];
    #pragma unroll
    for (int k = 0; k < 4; k++) { upv[k] = sp2[i0 + (k << 8)]; ugv[k] = sg2[i0 + (k << 8)]; }
    float aLm = 0.0f, aPe = 0.0f;
    int aCnt = 0;
    #pragma unroll
    for (int k = 0; k < 4; k++) {
        uintT up = upv[k], ug = ugv[k];
        if (!__any(up | ug)) continue;   // whole wave background
        float pe0 = 0.0f, pe1 = 0.0f;
        {
            int fp = up & 0xffff, fg = ug & 0xffff;
            if (fp) {
                if (!hasGt) pe0 = 1.0f;
                else {
                    float v = vP[fp - 1];
                    if (v > -2.5f) { if (v < 0.0f) pe0 = 1.0f; else if (!fg) pe0 = v; }
                }
            }
            if (fg) {
                float vg = vG[fg - 1];
                if (!fp) pe0 = fmaxf(pe0, fmaxf(vg, 0.0f));
                if (vg < 0.0f) pe0 = 1.0f;
            }
        }
        {
            int fp = up >> 16, fg = ug >> 16;
            if (fp) {
                if (!hasGt) pe1 = 1.0f;
                else {
                    float v = vP[fp - 1];
                    if (v > -2.5f) { if (v < 0.0f) pe1 = 1.0f; else if (!fg) pe1 = v; }
                }
            }
            if (fg) {
                float vg = vG[fg - 1];
                if (!fp) pe1 = fmaxf(pe1, fmaxf(vg, 0.0f));
                if (vg < 0.0f) pe1 = 1.0f;
            }
        }
        if (pe0 != 0.0f || pe1 != 0.0f) {
            float2 x2 = in2[i0 + (k << 8)];
            if (pe0 != 0.0f) {
                float score = 1.0f / (1.0f + __expf(-x2.x));
                aLm += (1.0f / (1.0f + __expf(-(score + 1.0f) * pe0)) - 0.5f) * 2.0f;
                aPe += pe0; aCnt++;
            }
            if (pe1 != 0.0f) {
                float score = 1.0f / (1.0f + __expf(-x2.y));
                aLm += (1.0f / (1.0f + __expf(-(score + 1.0f) * pe1)) - 0.5f) * 2.0f;
                aPe += pe1; aCnt++;
            }
        }
    }
    for (int o = 32; o; o >>= 1) {
        aLm += __shfl_xor(aLm, o);
        aPe += __shfl_xor(aPe, o);
        aCnt += __shfl_xor(aCnt, o);
    }
    int wv = threadIdx.x >> 6, lane = threadIdx.x & 63;
    if (lane == 0) { pLm[wv] = aLm; pPe[wv] = aPe; pCnt[wv] = aCnt; }
    __syncthreads();
    if (threadIdx.x == 0) {
        double sl = 0, sp = 0; int sc = 0;
        for (int q = 0; q < 4; q++) { sl += pLm[q]; sp += pPe[q]; sc += pCnt[q]; }
        partLm[blockIdx.x] = sl;
        partPe[blockIdx.x] = sp;
        partCnt[blockIdx.x] = (double)sc;
    }
}

// single-block reduction of the per-block partials -> 3 outputs
__global__ __launch_bounds__(TPB) void k_out(const double* __restrict__ partLm,
                                             const double* __restrict__ partPe,
                                             const double* __restrict__ partCnt,
                                             float* __restrict__ out) {
    __shared__ double r0[TPB], r1[TPB], r2[TPB];
    double sl = 0, sp = 0, sc = 0;
    for (int i = threadIdx.x; i < NFIN; i += TPB) {
        sl += partLm[i]; sp += partPe[i]; sc += partCnt[i];
    }
    r0[threadIdx.x] = sl; r1[threadIdx.x] = sp; r2[threadIdx.x] = sc;
    __syncthreads();
    for (int s = TPB >> 1; s > 0; s >>= 1) {
        if (threadIdx.x < s) {
            r0[threadIdx.x] += r0[threadIdx.x + s];
            r1[threadIdx.x] += r1[threadIdx.x + s];
            r2[threadIdx.x] += r2[threadIdx.x + s];
        }
        __syncthreads();
    }
    if (threadIdx.x == 0) {
        out[0] = (float)(r0[0] / (double)PN);
        out[1] = (float)(1.0 - r1[0] / (double)PN);
        out[2] = (float)(1.0 - r1[0] / r2[0]);
    }
}

extern "C" void kernel_launch(void* const* d_in, const int* in_sizes, int n_in,
                              void* d_out, int out_size, void* d_ws, size_t ws_size,
                              hipStream_t stream) {
    const float* in = (const float*)d_in[0];
    const float* tg = (const float*)d_in[1];
    // d_in[2] = epoch, unused by forward

    char* w = (char*)d_ws;
    size_t off = 0;
    ullT* rmP = (ullT*)(w + off); off += (size_t)(PN / 64) * 8;
    ullT* rmG = (ullT*)(w + off); off += (size_t)(PN / 64) * 8;
    ushortT* slotP = (ushortT*)(w + off); off += (size_t)PN * 2;
    ushortT* slotG = (ushortT*)(w + off); off += (size_t)PN * 2;
    int* parP = (int*)(w + off); off += (size_t)NB * CCAP * 4;
    int* parG = (int*)(w + off); off += (size_t)NB * CCAP * 4;
    ullT* cmLP = (ullT*)(w + off); off += (size_t)NB * 64 * 8;
    ullT* cmRP = (ullT*)(w + off); off += (size_t)NB * 64 * 8;
    ullT* cmLG = (ullT*)(w + off); off += (size_t)NB * 64 * 8;
    ullT* cmRG = (ullT*)(w + off); off += (size_t)NB * 64 * 8;
    float* vPs = (float*)(w + off); off += (size_t)NB * CCAP * 4;
    float* vGs = (float*)(w + off); off += (size_t)NB * CCAP * 4;
    int* ccntG = (int*)(w + off); off += NB * 4;
    double* partLm = (double*)(w + off); off += (size_t)NFIN * 8;
    double* partPe = (double*)(w + off); off += (size_t)NFIN * 8;
    double* partCnt = (double*)(w + off); off += (size_t)NFIN * 8;
    int* sAreaP = (int*)(w + off); off += (size_t)NB * CCAP * 4;
    int* sRP    = (int*)(w + off); off += (size_t)NB * CCAP * 4;
    int* sCP    = (int*)(w + off); off += (size_t)NB * CCAP * 4;
    int* sOvP   = (int*)(w + off); off += (size_t)NB * CCAP * 4;
    int* sAreaG = (int*)(w + off); off += (size_t)NB * CCAP * 4;
    int* sRG    = (int*)(w + off); off += (size_t)NB * CCAP * 4;
    int* sCG    = (int*)(w + off); off += (size_t)NB * CCAP * 4;
    int* sOvG   = (int*)(w + off); off += (size_t)NB * CCAP * 4;
    size_t zoff = off;
    int* candCntP = (int*)(w + off); off += NB * 4;
    int* candCntG = (int*)(w + off); off += NB * 4;
    size_t zend = off;

    // zero only the per-image candidate counters (128 B); slot stats are
    // self-zeroed by the allocating block in k_local phase 3b.
    hipMemsetAsync(w + zoff, 0, zend - zoff, stream);

    k_prep<<<2048, TPB, 0, stream>>>(in, tg, rmP, rmG);
    k_local<<<NB * 64 * 2, TPB, 0, stream>>>(rmP, rmG, slotP, slotG, parP, parG,
                                             cmLP, cmRP, cmLG, cmRG,
                                             candCntP, candCntG,
                                             sAreaP, sRP, sCP, sOvP,
                                             sAreaG, sRG, sCG, sOvG);
    {
        const int totalWaves = NB * 168;                    // 2688
        k_bmerge<<<(totalWaves + 3) / 4, TPB, 0, stream>>>(rmP, rmG, cmLP, cmRP, cmLG, cmRG,
                                                           slotP, slotG, parP, parG);
    }
    k_post<<<NB, 512, 0, stream>>>(parP, parG, candCntP, candCntG,
                                   sAreaP, sRP, sCP, sOvP,
                                   sAreaG, sRG, sCG, sOvG,
                                   ccntG, vPs, vGs);
    k_final<<<NFIN, TPB, 0, stream>>>(in, slotP, slotG, vPs, vGs, ccntG,
                                      partLm, partPe, partCnt);
    k_out<<<1, TPB, 0, stream>>>(partLm, partPe, partCnt, (float*)d_out);
}

// Round 20
// 133.617 us; speedup vs baseline: 1.3293x; 1.0041x over previous
//
#include <hip/hip_runtime.h>

#define NB 16
#define HH 512
#define WW 512
#define HWN (HH * WW)            // 262144 = 1<<18
#define KC 512                    // max regions kept per image
#define RCAP 4096                 // root list capacity per image
#define CCAP 4096                 // tile-root slot capacity per image
#define PN (NB * HWN)
#define TPB 256
#define IMAX 0x7FFFFFFF
#define TS 64                     // CCL tile side
#define TSQ (TS * TS)             // 4096, local sentinel
#define NFIN (NB * 128)           // k_final grid (2048 blocks)

typedef unsigned short ushortT;
typedef unsigned int uintT;
typedef unsigned long long ullT;

// ---------------- union-find helpers (LDS, pixel-in-tile) ----------------
__device__ __forceinline__ int findRootL(int* s, int i) {
    int p = s[i];
    while (p != i) { i = p; p = s[i]; }
    return i;
}

__device__ __forceinline__ void uniteL(int* s, int a, int b) {
    int ra = findRootL(s, a);
    int rb = findRootL(s, b);
    while (ra != rb) {
        int lo = min(ra, rb), hi = max(ra, rb);
        int old = atomicMin(&s[hi], lo);
        if (old == hi) return;
        ra = old; rb = lo;
    }
}

// ---------------- union-find (global, slot space, packed key<<12|slot) ----
// Monotone atomicMin: parent entries only decrease; min-key root wins.
__device__ __forceinline__ int rootPk(const int* __restrict__ par, int s) {
    int q = par[s];
    while ((q & (CCAP - 1)) != s) { s = q & (CCAP - 1); q = par[s]; }
    return q;                      // packed (key<<12|slot) of root
}

__device__ __forceinline__ void uniteS(int* par, int a, int b) {
    int pa = rootPk(par, a);
    int pb = rootPk(par, b);
    while (pa != pb) {
        int lo = min(pa, pb), hi = max(pa, pb);
        int hs = hi & (CCAP - 1);
        int old = atomicMin(&par[hs], lo);
        if (old == hi) return;
        pa = rootPk(par, old & (CCAP - 1));
        pb = rootPk(par, lo & (CCAP - 1));
    }
}

// binary search exact key in ascending array of KC ints (padded IMAX)
__device__ __forceinline__ int bsearch_k(const int* a, int key) {
    int lo = 0, hi = KC;
    while (lo < hi) { int m = (lo + hi) >> 1; if (a[m] < key) lo = m + 1; else hi = m; }
    return (lo < KC && a[lo] == key) ? lo : -1;
}

// ---------------- kernels ----------------
// Streaming prepass (float4-vectorized): threshold both masks, assemble
// 64-bit row-chunk masks via 16-lane shfl-OR reduction.
// Layout: rm[((tc*NB + b) << 9) + r]  (tc = column chunk 0..7).
__global__ __launch_bounds__(TPB) void k_prep(const float* __restrict__ in, const float* __restrict__ tg,
                                              ullT* __restrict__ rmP, ullT* __restrict__ rmG) {
    int lane = threadIdx.x & 63;
    int wid = (blockIdx.x * blockDim.x + threadIdx.x) >> 6;   // 8192 waves
    const float4* in4 = (const float4*)in;
    const float4* tg4 = (const float4*)tg;
    #pragma unroll
    for (int it = 0; it < 2; it++) {
        int span = wid + (it << 13);          // 16384 spans of 256 px
        int vidx = (span << 6) + lane;        // float4 index
        float4 a = in4[vidx];
        float4 t4 = tg4[vidx];
        uintT bp = (a.x > 0.0f) | ((a.y > 0.0f) << 1) | ((a.z > 0.0f) << 2) | ((a.w > 0.0f) << 3);
        uintT bg = (t4.x > 0.5f) | ((t4.y > 0.5f) << 1) | ((t4.z > 0.5f) << 2) | ((t4.w > 0.5f) << 3);
        ullT vp = (ullT)bp << ((lane & 15) << 2);
        ullT vg = (ullT)bg << ((lane & 15) << 2);
        #pragma unroll
        for (int o = 1; o < 16; o <<= 1) {
            vp |= __shfl_xor(vp, o);
            vg |= __shfl_xor(vg, o);
        }
        if ((lane & 15) == 0) {
            int g = (span << 8) + ((lane >> 4) << 6);
            int b = g >> 18, r = (g >> 9) & 511, tc = (g >> 6) & 7;
            int idx = (((tc << 4) + b) << 9) + r;
            rmP[idx] = vp; rmG[idx] = vg;
        }
    }
}

// Per-(tile,mask) CCL from row masks. Phase 3a merged into 3c: pixels chase
// to the first NEGATIVE entry (roots are negated in 3b), with racy
// path-compression write-back.
__global__ __launch_bounds__(TPB) void k_local(const ullT* __restrict__ rmPArr, const ullT* __restrict__ rmGArr,
                        ushortT* __restrict__ slotP, ushortT* __restrict__ slotG,
                        int* __restrict__ parP, int* __restrict__ parG,
                        ullT* __restrict__ cmLP, ullT* __restrict__ cmRP,
                        ullT* __restrict__ cmLG, ullT* __restrict__ cmRG,
                        int* __restrict__ candCntP, int* __restrict__ candCntG,
                        int* __restrict__ sAreaP, int* __restrict__ sRP, int* __restrict__ sCP, int* __restrict__ sOvP,
                        int* __restrict__ sAreaG, int* __restrict__ sRG, int* __restrict__ sCG, int* __restrict__ sOvG) {
    __shared__ int s[TSQ];
    __shared__ ullT rm[TS], rmO[TS];
    int side = blockIdx.x & 1;
    int tileIdx = blockIdx.x >> 1;
    int b = tileIdx >> 6;               // 64 tiles per image (8x8)
    int tile = tileIdx & 63;
    int r0 = (tile >> 3) << 6, c0 = (tile & 7) << 6;
    int tc = tile & 7;
    int base = (b << 18) + (r0 << 9) + c0;
    int wv = threadIdx.x >> 6, lane = threadIdx.x & 63;

    const ullT* own = side ? rmGArr : rmPArr;
    const ullT* oth = side ? rmPArr : rmGArr;
    ushortT* slotArr = side ? slotG : slotP;
    int* par  = side ? parG : parP;
    ullT* cmLo = side ? cmLG : cmLP;
    ullT* cmRo = side ? cmRG : cmRP;
    int* candCnt = side ? candCntG : candCntP;
    int* sArea = side ? sAreaG : sAreaP;
    int* sR = side ? sRG : sRP;
    int* sC = side ? sCG : sCP;
    int* sOv = side ? sOvG : sOvP;

    // phase 0: load 64+64 row masks (512B each, contiguous)
    int rowIdx = (((tc << 4) + b) << 9) + r0;
    if (threadIdx.x < 64) rm[threadIdx.x] = own[rowIdx + threadIdx.x];
    else if (threadIdx.x < 128) rmO[threadIdx.x - 64] = oth[rowIdx + threadIdx.x - 64];
    __syncthreads();

    // phase 0b: export edge-column masks (wave 0: lane = row)
    if (threadIdx.x < 64) {
        ullT v = rm[threadIdx.x];
        ullT mL = __ballot((v & 1ULL) != 0);
        ullT mR = __ballot((v >> 63) != 0);
        if (threadIdx.x == 0) { cmLo[tileIdx] = mL; cmRo[tileIdx] = mR; }
    }

    // phase 1: run-start initial labels (no atomics, no ballots)
    #pragma unroll
    for (int k = 0; k < 16; k++) {
        int lr = wv + (k << 2);
        ullT mp = rm[lr];
        bool p = (mp >> lane) & 1ULL;
        int t = (lr << 6) + lane;
        ullT below = (lane == 0) ? 0ULL : ((~mp) & ((1ULL << lane) - 1ULL));
        int st = below ? (64 - __clzll(below)) : 0;
        s[t] = p ? ((lr << 6) + st) : TSQ;
    }
    __syncthreads();

    // phase 2: inter-row unions, reduced rules
    for (int lr = wv; lr < TS; lr += 4) {
        if (lr == 0) continue;
        int t = (lr << 6) + lane;
        ullT m = rm[lr], a = rm[lr - 1];
        if ((m >> lane) & 1ULL) {
            bool N  = (a >> lane) & 1ULL;
            bool W  = lane > 0  && ((m >> (lane - 1)) & 1ULL);
            bool NW = lane > 0  && ((a >> (lane - 1)) & 1ULL);
            bool E  = lane < 63 && ((m >> (lane + 1)) & 1ULL);
            bool NE = lane < 63 && ((a >> (lane + 1)) & 1ULL);
            if (N) { if (!(W && NW)) uniteL(s, t, t - TS); }
            else {
                if (NW && !W) uniteL(s, t, t - TS - 1);
                if (NE && !E) uniteL(s, t, t - TS + 1);
            }
        }
    }
    __syncthreads();

    // phase 3b: roots -> slots (negate root entries; NON-chasing self test),
    // packed par init, stats self-zero.
    #pragma unroll
    for (int k = 0; k < 16; k++) {
        int t = ((wv + (k << 2)) << 6) + lane;
        if (s[t] == t) {                           // root: self-pointing entry
            int pos = atomicAdd(&candCnt[b], 1);
            if (pos >= CCAP) pos = CCAP - 1;
            int gl = ((r0 + (t >> 6)) << 9) + (c0 + (t & 63));
            par[b * CCAP + pos] = (gl << 12) | pos;
            sArea[b * CCAP + pos] = 0;
            sR[b * CCAP + pos] = 0;
            sC[b * CCAP + pos] = 0;
            sOv[b * CCAP + pos] = 0;
            s[t] = -(pos + 2);
        }
    }
    __syncthreads();

    // phase 3c: chase-to-negative slot resolution (racy compression),
    // per-pixel slot write + per-run stats. After 3b all roots are negative;
    // positive chains strictly decrease and terminate at a negative.
    #pragma unroll
    for (int k = 0; k < 16; k++) {
        int lr = wv + (k << 2);
        int t = (lr << 6) + lane;
        int g = base + (lr << 9) + lane;
        int vp = s[t];
        int slot = 0;
        if (vp != TSQ) {
            if (vp < 0) slot = -vp - 1;              // root: slot = pos+1
            else {
                int cur = vp;
                int v = s[cur];
                while (v >= 0) { cur = v; v = s[cur]; }
                slot = -v - 1;
                if (cur != vp) s[t] = cur;           // racy compression, safe
            }
        }
        slotArr[g] = (ushortT)slot;
        // run stats (run-start lanes only)
        ullT mp = rm[lr], mq = rmO[lr];
        bool isF = (mp >> lane) & 1ULL;
        if (isF && (lane == 0 || !((mp >> (lane - 1)) & 1ULL))) {
            ullT x = ~(mp >> lane);
            int len = x ? (__ffsll((long long)x) - 1) : (64 - lane);
            int sl = slot - 1;
            ullT runbits = (len >= 64) ? ~0ULL : (((1ULL << len) - 1ULL) << lane);
            atomicAdd(&sArea[b * CCAP + sl], len);
            atomicAdd(&sR[b * CCAP + sl], (r0 + lr) * len);
            atomicAdd(&sC[b * CCAP + sl], len * (c0 + lane) + (len * (len - 1)) / 2);
            if (mq & runbits) atomicOr(&sOv[b * CCAP + sl], 1);
        }
    }
}

// Mask-driven cross-tile merges. One wave per (image, type, q, t8); only
// union-firing lanes touch the slot arrays.
__global__ __launch_bounds__(TPB) void k_bmerge(
        const ullT* __restrict__ rmP, const ullT* __restrict__ rmG,
        const ullT* __restrict__ cmLP, const ullT* __restrict__ cmRP,
        const ullT* __restrict__ cmLG, const ullT* __restrict__ cmRG,
        const ushortT* __restrict__ slotP, const ushortT* __restrict__ slotG,
        int* __restrict__ parP, int* __restrict__ parG) {
    int wid = (blockIdx.x << 2) + (threadIdx.x >> 6);   // 2688 waves
    int lane = threadIdx.x & 63;
    int b = wid / 168;
    int rem = wid % 168;
    int type = rem / 56;
    int sub = rem % 56;
    int q = sub >> 3, t8 = sub & 7;

    for (int side = 0; side < 2; side++) {
        const ullT* rm = side ? rmG : rmP;
        const ullT* cmL = side ? cmLG : cmLP;
        const ullT* cmR = side ? cmRG : cmRP;
        const ushortT* S = (side ? slotG : slotP) + (b << 18);
        int* par = (side ? parG : parP) + b * CCAP;

        if (type == 0) {
            int r = (q + 1) << 6, tc = t8;
            int ib = (((tc << 4) + b) << 9);
            ullT m = rm[ib + r];
            if (!m) continue;
            ullT a = rm[ib + r - 1];
            ullT mW = 0, aW = 0, mE = 0, aE = 0;
            if (tc > 0) { int iw = ((((tc - 1) << 4) + b) << 9); mW = rm[iw + r]; aW = rm[iw + r - 1]; }
            if (tc < 7) { int ie = ((((tc + 1) << 4) + b) << 9); mE = rm[ie + r]; aE = rm[ie + r - 1]; }
            if ((m >> lane) & 1ULL) {
                bool N  = (a >> lane) & 1ULL;
                bool W  = lane ? ((m >> (lane - 1)) & 1ULL) : ((mW >> 63) & 1ULL);
                bool NW = lane ? ((a >> (lane - 1)) & 1ULL) : ((aW >> 63) & 1ULL);
                bool E  = (lane < 63) ? ((m >> (lane + 1)) & 1ULL) : (mE & 1ULL);
                bool NE = (lane < 63) ? ((a >> (lane + 1)) & 1ULL) : (aE & 1ULL);
                int i = (r << 9) + (tc << 6) + lane;
                if (N) {
                    if (!(W && NW)) uniteS(par, S[i] - 1, S[i - WW] - 1);
                } else {
                    if (NW && !W) uniteS(par, S[i] - 1, S[i - WW - 1] - 1);
                    if (NE && !E) uniteS(par, S[i] - 1, S[i - WW + 1] - 1);
                }
            }
        } else if (type == 1) {
            int c = (q + 1) << 6, tr = t8;
            int ownT = (b << 6) + (tr << 3) + (q + 1);
            int wstT = ownT - 1;
            ullT co = cmL[ownT];
            if (!co) continue;
            ullT cw = cmR[wstT];
            ullT coA = 0, cwA = 0;
            if (tr > 0) { coA = cmL[ownT - 8]; cwA = cmR[wstT - 8]; }
            int r = lane;
            if ((co >> r) & 1ULL) {
                bool W  = (cw >> r) & 1ULL;
                bool pO = r ? ((co >> (r - 1)) & 1ULL) : ((coA >> 63) & 1ULL);
                bool pW = r ? ((cw >> (r - 1)) & 1ULL) : ((cwA >> 63) & 1ULL);
                int i = (((tr << 6) + r) << 9) + c;
                if (r == 0) {   // conservative at tile-top (breaks skip cycle)
                    if (W) uniteS(par, S[i] - 1, S[i - 1] - 1);
                    else if (pW) uniteS(par, S[i] - 1, S[i - WW - 1] - 1);
                } else {
                    if (W) { if (!(pO && pW)) uniteS(par, S[i] - 1, S[i - 1] - 1); }
                    else if (pW && !pO) uniteS(par, S[i] - 1, S[i - WW - 1] - 1);
                }
            }
        } else {
            int c = (q << 6) + 63, tr = t8;
            int ownT = (b << 6) + (tr << 3) + q;
            int estT = ownT + 1;
            ullT co = cmR[ownT];
            if (!co) continue;
            ullT ce = cmL[estT];
            ullT coA = 0, ceA = 0;
            if (tr > 0) { coA = cmR[ownT - 8]; ceA = cmL[estT - 8]; }
            int r = lane;
            if ((co >> r) & 1ULL) {
                bool E  = (ce >> r) & 1ULL;
                bool NE = r ? ((ce >> (r - 1)) & 1ULL) : ((ceA >> 63) & 1ULL);
                bool pO = r ? ((co >> (r - 1)) & 1ULL) : false;   // conservative at r=0
                if (NE && !E && !pO) {
                    int i = (((tr << 6) + r) << 9) + c;
                    uniteS(par, S[i] - 1, S[i - WW + 1] - 1);
                }
            }
        }
    }
}

// One block per IMAGE (512 thr): filter+sort root keys (both masks), slot->cid
// redux with LDS stats, centroid match, scatter per-slot value tables.
__global__ __launch_bounds__(512) void k_post(
        const int* __restrict__ parP, const int* __restrict__ parG,
        const int* __restrict__ candCntP, const int* __restrict__ candCntG,
        const int* __restrict__ sAreaP, const int* __restrict__ sRP, const int* __restrict__ sCP, const int* __restrict__ sOvP,
        const int* __restrict__ sAreaG, const int* __restrict__ sRG, const int* __restrict__ sCG, const int* __restrict__ sOvG,
        int* __restrict__ ccntG_g, float* __restrict__ vPs, float* __restrict__ vGs) {
    __shared__ int s[RCAP];                       // sort buffer, later cid store
    __shared__ int compL[2][KC];
    __shared__ int stA[2][KC], stR[2][KC], stC[2][KC], stOv[2][KC];
    __shared__ float gAf[KC], gRf[KC], gCf[KC], sEG[KC], sFPl[KC], sFGl[KC];
    __shared__ int lcnt, ccX[2];
    int b = blockIdx.x;
    int tid = threadIdx.x;

    // A: filter root slots + sort their pixel keys, build compact tables
    for (int side = 0; side < 2; side++) {
        const int* par = (side ? parG : parP) + b * CCAP;
        int n = min((side ? candCntG : candCntP)[b], CCAP);
        if (tid == 0) lcnt = 0;
        __syncthreads();
        for (int t = tid; t < n; t += 512) {
            int pk = par[t];
            if ((pk & (CCAP - 1)) == t) { int pos = atomicAdd(&lcnt, 1); if (pos < RCAP) s[pos] = pk >> 12; }
        }
        __syncthreads();
        int nn2 = min(lcnt, RCAP);
        int m = 1; while (m < nn2) m <<= 1;
        for (int t = nn2 + tid; t < m; t += 512) s[t] = IMAX;
        __syncthreads();
        for (int k = 2; k <= m; k <<= 1) {
            for (int j = k >> 1; j > 0; j >>= 1) {
                for (int t = tid; t < m; t += 512) {
                    int ixj = t ^ j;
                    if (ixj > t) {
                        int a = s[t], bb = s[ixj];
                        bool up = ((t & k) == 0);
                        if ((a > bb) == up) { s[t] = bb; s[ixj] = a; }
                    }
                }
                __syncthreads();
            }
        }
        int cc = min(nn2, KC);
        for (int t = tid; t < KC; t += 512)
            compL[side][t] = (t < cc) ? s[t] : IMAX;
        if (tid == 0) { ccX[side] = cc; if (side) ccntG_g[b] = cc; }
        __syncthreads();
    }

    // B: zero LDS cid stats
    for (int t = tid; t < KC; t += 512) {
        stA[0][t] = 0; stR[0][t] = 0; stC[0][t] = 0; stOv[0][t] = 0;
        stA[1][t] = 0; stR[1][t] = 0; stC[1][t] = 0; stOv[1][t] = 0;
    }
    __syncthreads();

    // C: per-slot chase (packed forest, L2-hot) + bsearch + aggregate
    short* cidS = (short*)s;
    for (int side = 0; side < 2; side++) {
        const int* par = (side ? parG : parP) + b * CCAP;
        const int* aA = side ? sAreaG : sAreaP;
        const int* aR = side ? sRG : sRP;
        const int* aC = side ? sCG : sCP;
        const int* aO = side ? sOvG : sOvP;
        int n = min((side ? candCntG : candCntP)[b], CCAP);
        for (int slot = tid; slot < n; slot += 512) {
            int pk = rootPk(par, slot);
            int cid = bsearch_k(compL[side], pk >> 12);
            cidS[side * CCAP + slot] = (short)cid;
            if (cid >= 0) {
                int sidx = b * CCAP + slot;
                atomicAdd(&stA[side][cid], aA[sidx]);
                atomicAdd(&stR[side][cid], aR[sidx]);
                atomicAdd(&stC[side][cid], aC[sidx]);
                if (aO[sidx]) atomicOr(&stOv[side][cid], 1);
            }
        }
    }
    __syncthreads();

    // D: nearest gt centroid per pred region, region errors
    int t = tid;                                   // 512 == KC
    int ccg = ccX[1], ccp = ccX[0];
    {
        float fa = (float)stA[1][t];
        float d = fmaxf(fa, 1.0f);
        gAf[t] = fa;
        gRf[t] = (float)stR[1][t] / d;
        gCf[t] = (float)stC[1][t] / d;
        sEG[t] = 0.0f;
    }
    __syncthreads();
    float e_eff = 0.0f;
    int nn = 0;
    if (t < ccp) {
        float pa = (float)stA[0][t];
        float dd = fmaxf(pa, 1.0f);
        float pcr = (float)stR[0][t] / dd;
        float pcc = (float)stC[0][t] / dd;
        float best = INFINITY;
        for (int gi = 0; gi < ccg; gi++) {
            float dr = pcr - gRf[gi], dc = pcc - gCf[gi];
            float d2 = dr * dr + dc * dc;
            if (d2 < best) { best = d2; nn = gi; }  // first-min ties like argmin
        }
        if (ccg > 0 && stOv[0][t]) {
            float ratio = 1.0f - gAf[nn] / dd;
            e_eff = fminf(fabsf(1.0f - __expf(ratio)), 1.0f);
        }
    }
    if (e_eff > 0.0f) atomicMax((int*)&sEG[nn], __float_as_int(e_eff));
    sFPl[t] = stOv[0][t] ? e_eff : -1.0f;
    __syncthreads();
    sFGl[t] = stOv[1][t] ? fmaxf(sEG[t], 0.0f) : -1.0f;
    __syncthreads();

    // E: scatter per-slot value tables
    int nP = min(candCntP[b], CCAP), nG = min(candCntG[b], CCAP);
    for (int s2 = tid; s2 < nP; s2 += 512) {
        int cid = cidS[s2];
        vPs[b * CCAP + s2] = (cid >= 0) ? sFPl[cid] : -3.0f;   // -3 = fg w/o compact id
    }
    for (int s2 = tid; s2 < nG; s2 += 512) {
        int cid = cidS[CCAP + s2];
        vGs[b * CCAP + s2] = (cid >= 0) ? sFGl[cid] : 0.0f;
    }
}

// per-pixel error rules + fused loss/metric reduction: pure table lookups.
// 2 pixels per thread; batched register loads; per-block partial stores.
__global__ __launch_bounds__(TPB) void k_final(const float* __restrict__ in,
                        const ushortT* __restrict__ slotP, const ushortT* __restrict__ slotG,
                        const float* __restrict__ vPs, const float* __restrict__ vGs,
                        const int* __restrict__ ccntG,
                        double* __restrict__ partLm, double* __restrict__ partPe,
                        double* __restrict__ partCnt) {
    __shared__ float pLm[4], pPe[4];
    __shared__ int pCnt[4];
    const uintT* sp2 = (const uintT*)slotP;
    const uintT* sg2 = (const uintT*)slotG;
    const float2* in2 = (const float2*)in;
    int b = blockIdx.x >> 7;            // 128 blocks per image, 1024 pairs each
    int blk = blockIdx.x & 127;
    bool hasGt = ccntG[b] > 0;
    const float* vP = vPs + b * CCAP;
    const float* vG = vGs + b * CCAP;
    int i0 = (b << 17) + (blk << 10) + threadIdx.x;
    // batched loads: 8 independent loads in flight
    uintT upv[4], ugv[4];
    #pragma unroll
    for (int k = 0; k < 4; k++) { upv[k] = sp2[i0 + (k << 8)]; ugv[k] = sg2[i0 + (k << 8)]; }
    float aLm = 0.0f, aPe = 0.0f;
    int aCnt = 0;
    #pragma unroll
    for (int k = 0; k < 4; k++) {
        uintT up = upv[k], ug = ugv[k];
        if (!__any(up | ug)) continue;   // whole wave background
        float pe0 = 0.0f, pe1 = 0.0f;
        {
            int fp = up & 0xffff, fg = ug & 0xffff;
            if (fp) {
                if (!hasGt) pe0 = 1.0f;
                else {
                    float v = vP[fp - 1];
                    if (v > -2.5f) { if (v < 0.0f) pe0 = 1.0f; else if (!fg) pe0 = v; }
                }
            }
            if (fg) {
                float vg = vG[fg - 1];
                if (!fp) pe0 = fmaxf(pe0, fmaxf(vg, 0.0f));
                if (vg < 0.0f) pe0 = 1.0f;
            }
        }
        {
            int fp = up >> 16, fg = ug >> 16;
            if (fp) {
                if (!hasGt) pe1 = 1.0f;
                else {
                    float v = vP[fp - 1];
                    if (v > -2.5f) { if (v < 0.0f) pe1 = 1.0f; else if (!fg) pe1 = v; }
                }
            }
            if (fg) {
                float vg = vG[fg - 1];
                if (!fp) pe1 = fmaxf(pe1, fmaxf(vg, 0.0f));
                if (vg < 0.0f) pe1 = 1.0f;
            }
        }
        if (pe0 != 0.0f || pe1 != 0.0f) {
            float2 x2 = in2[i0 + (k << 8)];
            if (pe0 != 0.0f) {
                float score = 1.0f / (1.0f + __expf(-x2.x));
                aLm += (1.0f / (1.0f + __expf(-(score + 1.0f) * pe0)) - 0.5f) * 2.0f;
                aPe += pe0; aCnt++;
            }
            if (pe1 != 0.0f) {
                float score = 1.0f / (1.0f + __expf(-x2.y));
                aLm += (1.0f / (1.0f + __expf(-(score + 1.0f) * pe1)) - 0.5f) * 2.0f;
                aPe += pe1; aCnt++;
            }
        }
    }
    for (int o = 32; o; o >>= 1) {
        aLm += __shfl_xor(aLm, o);
        aPe += __shfl_xor(aPe, o);
        aCnt += __shfl_xor(aCnt, o);
    }
    int wv = threadIdx.x >> 6, lane = threadIdx.x & 63;
    if (lane == 0) { pLm[wv] = aLm; pPe[wv] = aPe; pCnt[wv] = aCnt; }
    __syncthreads();
    if (threadIdx.x == 0) {
        double sl = 0, sp = 0; int sc = 0;
        for (int q = 0; q < 4; q++) { sl += pLm[q]; sp += pPe[q]; sc += pCnt[q]; }
        partLm[blockIdx.x] = sl;
        partPe[blockIdx.x] = sp;
        partCnt[blockIdx.x] = (double)sc;
    }
}

// single-block reduction of the per-block partials -> 3 outputs
__global__ __launch_bounds__(TPB) void k_out(const double* __restrict__ partLm,
                                             const double* __restrict__ partPe,
                                             const double* __restrict__ partCnt,
                                             float* __restrict__ out) {
    __shared__ double r0[TPB], r1[TPB], r2[TPB];
    double sl = 0, sp = 0, sc = 0;
    for (int i = threadIdx.x; i < NFIN; i += TPB) {
        sl += partLm[i]; sp += partPe[i]; sc += partCnt[i];
    }
    r0[threadIdx.x] = sl; r1[threadIdx.x] = sp; r2[threadIdx.x] = sc;
    __syncthreads();
    for (int s = TPB >> 1; s > 0; s >>= 1) {
        if (threadIdx.x < s) {
            r0[threadIdx.x] += r0[threadIdx.x + s];
            r1[threadIdx.x] += r1[threadIdx.x + s];
            r2[threadIdx.x] += r2[threadIdx.x + s];
        }
        __syncthreads();
    }
    if (threadIdx.x == 0) {
        out[0] = (float)(r0[0] / (double)PN);
        out[1] = (float)(1.0 - r1[0] / (double)PN);
        out[2] = (float)(1.0 - r1[0] / r2[0]);
    }
}

extern "C" void kernel_launch(void* const* d_in, const int* in_sizes, int n_in,
                              void* d_out, int out_size, void* d_ws, size_t ws_size,
                              hipStream_t stream) {
    const float* in = (const float*)d_in[0];
    const float* tg = (const float*)d_in[1];
    // d_in[2] = epoch, unused by forward

    char* w = (char*)d_ws;
    size_t off = 0;
    ullT* rmP = (ullT*)(w + off); off += (size_t)(PN / 64) * 8;
    ullT* rmG = (ullT*)(w + off); off += (size_t)(PN / 64) * 8;
    ushortT* slotP = (ushortT*)(w + off); off += (size_t)PN * 2;
    ushortT* slotG = (ushortT*)(w + off); off += (size_t)PN * 2;
    int* parP = (int*)(w + off); off += (size_t)NB * CCAP * 4;
    int* parG = (int*)(w + off); off += (size_t)NB * CCAP * 4;
    ullT* cmLP = (ullT*)(w + off); off += (size_t)NB * 64 * 8;
    ullT* cmRP = (ullT*)(w + off); off += (size_t)NB * 64 * 8;
    ullT* cmLG = (ullT*)(w + off); off += (size_t)NB * 64 * 8;
    ullT* cmRG = (ullT*)(w + off); off += (size_t)NB * 64 * 8;
    float* vPs = (float*)(w + off); off += (size_t)NB * CCAP * 4;
    float* vGs = (float*)(w + off); off += (size_t)NB * CCAP * 4;
    int* ccntG = (int*)(w + off); off += NB * 4;
    double* partLm = (double*)(w + off); off += (size_t)NFIN * 8;
    double* partPe = (double*)(w + off); off += (size_t)NFIN * 8;
    double* partCnt = (double*)(w + off); off += (size_t)NFIN * 8;
    int* sAreaP = (int*)(w + off); off += (size_t)NB * CCAP * 4;
    int* sRP    = (int*)(w + off); off += (size_t)NB * CCAP * 4;
    int* sCP    = (int*)(w + off); off += (size_t)NB * CCAP * 4;
    int* sOvP   = (int*)(w + off); off += (size_t)NB * CCAP * 4;
    int* sAreaG = (int*)(w + off); off += (size_t)NB * CCAP * 4;
    int* sRG    = (int*)(w + off); off += (size_t)NB * CCAP * 4;
    int* sCG    = (int*)(w + off); off += (size_t)NB * CCAP * 4;
    int* sOvG   = (int*)(w + off); off += (size_t)NB * CCAP * 4;
    size_t zoff = off;
    int* candCntP = (int*)(w + off); off += NB * 4;
    int* candCntG = (int*)(w + off); off += NB * 4;
    size_t zend = off;

    // zero only the per-image candidate counters (128 B); slot stats are
    // self-zeroed by the allocating block in k_local phase 3b.
    hipMemsetAsync(w + zoff, 0, zend - zoff, stream);

    k_prep<<<2048, TPB, 0, stream>>>(in, tg, rmP, rmG);
    k_local<<<NB * 64 * 2, TPB, 0, stream>>>(rmP, rmG, slotP, slotG, parP, parG,
                                             cmLP, cmRP, cmLG, cmRG,
                                             candCntP, candCntG,
                                             sAreaP, sRP, sCP, sOvP,
                                             sAreaG, sRG, sCG, sOvG);
    {
        const int totalWaves = NB * 168;                    // 2688
        k_bmerge<<<(totalWaves + 3) / 4, TPB, 0, stream>>>(rmP, rmG, cmLP, cmRP, cmLG, cmRG,
                                                           slotP, slotG, parP, parG);
    }
    k_post<<<NB, 512, 0, stream>>>(parP, parG, candCntP, candCntG,
                                   sAreaP, sRP, sCP, sOvP,
                                   sAreaG, sRG, sCG, sOvG,
                                   ccntG, vPs, vGs);
    k_final<<<NFIN, TPB, 0, stream>>>(in, slotP, slotG, vPs, vGs, ccntG,
                                      partLm, partPe, partCnt);
    k_out<<<1, TPB, 0, stream>>>(partLm, partPe, partCnt, (float*)d_out);
}